// Round 16
// baseline (365.263 us; speedup 1.0000x reference)
//
#include <hip/hip_runtime.h>
#include <math.h>

#define T_SEQ 2048
#define NHQ 32
#define NG 2
#define HD 64
#define CSTRIDE 16
#define KVGW 384  // fused k|v|gate row width: 128 k + 128 v + 3 gate + pad

// raw v_exp_f32 (computes 2^x). HIP's exp2f() is the PRECISE ocml version
// (~6 extra VALU ops: round-14 VALUBusy 37->50% regression); __expf is
// v_mul(log2e)+v_exp. The builtin is the single-instruction path.
#if defined(__has_builtin)
#if __has_builtin(__builtin_amdgcn_exp2f)
#define EXP2(x) __builtin_amdgcn_exp2f(x)
#endif
#endif
#ifndef EXP2
#define EXP2(x) __expf(0.6931471805599453f * (x))
#endif

typedef __attribute__((ext_vector_type(8))) short short8_t;
typedef __attribute__((ext_vector_type(4))) short short4_t;
typedef __attribute__((ext_vector_type(4))) float f32x4;

__device__ __forceinline__ ushort f2bf(float x) {  // round-to-nearest-even
  union { float f; unsigned u; } c; c.f = x;
  unsigned r = c.u + 0x7fff + ((c.u >> 16) & 1);
  return (ushort)(r >> 16);
}
__device__ __forceinline__ float bf2f(ushort u) {
  union { unsigned u; float f; } c; c.u = ((unsigned)u) << 16;
  return c.f;
}

__device__ __forceinline__ void glds16(const ushort* g, ushort* l) {
  __builtin_amdgcn_global_load_lds(
      (const __attribute__((address_space(1))) unsigned int*)g,
      (__attribute__((address_space(3))) unsigned int*)l, 16, 0, 0);
}

// ---- bf16 MFMA GEMM: C[M,N] = A[M,K] * B[N,K]^T (m97 recipe + XOR swizzle)
// v4: BM=128 x BN=64 tile, 512 thr = 8 waves (wave tile 32x32). Grid at
// N=2048 is 32x16 = 512 wgs = 2 wg/CU -> 16 waves/CU (was 8 with 4-wave
// wgs): doubles the m114 latency-hiding pool with identical tiles/traffic.
__global__ __launch_bounds__(512) void mgemm(
    const ushort* __restrict__ A, const ushort* __restrict__ B,
    float* __restrict__ C, int M, int N, int K) {
  __shared__ __align__(16) ushort As[128 * 64];
  __shared__ __align__(16) ushort Bs[64 * 64];
  const int tid = threadIdx.x;
  const int lane = tid & 63, w = tid >> 6;  // 8 waves
  const int quad = lane >> 4, l16 = lane & 15;
  const int m0 = blockIdx.y * 128, n0 = blockIdx.x * 64;
  const int mq = (w & 3) * 32, nq = (w >> 2) * 32;
  f32x4 acc[2][2];
  const f32x4 fz = {0.f, 0.f, 0.f, 0.f};
  #pragma unroll
  for (int i = 0; i < 2; ++i)
    #pragma unroll
    for (int j = 0; j < 2; ++j) acc[i][j] = fz;

  for (int k0 = 0; k0 < K; k0 += 64) {
    __syncthreads();
    #pragma unroll
    for (int j = 0; j < 2; ++j) {  // A: 128 rows x 8 chunks (1024 chunks)
      int ci = j * 512 + tid;
      int row = ci >> 3, cl = ci & 7;
      int kc = cl ^ (row & 7);
      glds16(A + ((size_t)(m0 + row) * K + k0 + kc * 8), &As[ci * 8]);
    }
    {  // B: 64 rows x 8 chunks (512 chunks)
      int ci = tid;
      int row = ci >> 3, cl = ci & 7;
      int kc = cl ^ (row & 7);
      glds16(B + ((size_t)(n0 + row) * K + k0 + kc * 8), &Bs[ci * 8]);
    }
    __syncthreads();
    #pragma unroll
    for (int kt = 0; kt < 2; ++kt) {
      short8_t af[2], bf_[2];
      #pragma unroll
      for (int mt = 0; mt < 2; ++mt) {
        int row = mq + mt * 16 + l16;
        int cl = (kt * 4 + quad) ^ (row & 7);
        af[mt] = *(const short8_t*)&As[row * 64 + cl * 8];
      }
      #pragma unroll
      for (int nt = 0; nt < 2; ++nt) {
        int row = nq + nt * 16 + l16;
        int cl = (kt * 4 + quad) ^ (row & 7);
        bf_[nt] = *(const short8_t*)&Bs[row * 64 + cl * 8];
      }
      #pragma unroll
      for (int mt = 0; mt < 2; ++mt)
        #pragma unroll
        for (int nt = 0; nt < 2; ++nt)
          acc[mt][nt] = __builtin_amdgcn_mfma_f32_16x16x32_bf16(
              af[mt], bf_[nt], acc[mt][nt], 0, 0, 0);
    }
  }
  #pragma unroll
  for (int mt = 0; mt < 2; ++mt)
    #pragma unroll
    for (int nt = 0; nt < 2; ++nt)
      #pragma unroll
      for (int r = 0; r < 4; ++r) {
        int m = m0 + mq + mt * 16 + quad * 4 + r;
        int n = n0 + nq + nt * 16 + l16;
        C[(size_t)m * N + n] = acc[mt][nt][r];
      }
}

// ---------------- conversions / packing (float4-vectorized, G13) ----------
__global__ __launch_bounds__(256) void cvt_bf(const float* __restrict__ src,
                                              ushort* __restrict__ dst, int n) {
  int i = (blockIdx.x * 256 + threadIdx.x) * 4;
  if (i >= n) return;
  float4 v = *(const float4*)(src + i);
  short4_t o = {(short)f2bf(v.x), (short)f2bf(v.y),
                (short)f2bf(v.z), (short)f2bf(v.w)};
  *(short4_t*)(dst + i) = o;
}

__global__ __launch_bounds__(256) void pack_wkvg(
    const float* __restrict__ Wk, const float* __restrict__ Wv,
    const float* __restrict__ Wg, ushort* __restrict__ dst) {
  int i = blockIdx.x * 256 + threadIdx.x;
  if (i >= KVGW * 2048) return;
  int n = i >> 11, k = i & 2047;
  float v;
  if (n < 128) v = Wk[(size_t)n * 2048 + k];
  else if (n < 256) v = Wv[(size_t)(n - 128) * 2048 + k];
  else if (n < 259) v = Wg[(size_t)(n - 256) * 2048 + k];
  else v = 0.f;
  dst[i] = f2bf(v);
}

// vt[g][d][*] bf16 from kvg v-part (v is NOT roped), with an 8B-slot
// permutation baked into each 64-key block: key k of block blk is stored at
// blk*64 + ((k>>2)^(d&15))*4 + (k&3). mfma_attn stages rows LINEARLY and
// reads slot (kt*4+quad)^l16 -> conflict-free b64 phases (verified r7: 6.39M->0).
__global__ __launch_bounds__(256) void cvt_vt(const float* __restrict__ kvg,
                                              ushort* __restrict__ vt) {
  int i = blockIdx.x * 256 + threadIdx.x;
  if (i >= T_SEQ * NG * HD) return;
  int d = i & 63, g = (i >> 6) & 1, s = i >> 7;
  int blk = s >> 6, k = s & 63;
  int snew = blk * 64 + (((k >> 2) ^ (d & 15)) << 2) + (k & 3);
  vt[((size_t)g * HD + d) * T_SEQ + snew] =
      f2bf(kvg[(size_t)s * KVGW + 128 + g * 64 + d]);
}

// ------- RoPE: q fp32 -> qbf bf16 PRE-SCALED by 0.125*log2(e) so attention
// scores are in the log2 domain: softmax uses raw v_exp_f32 (EXP2) with no
// per-element log2e multiply. Softmax is base-invariant after normalization.
// kvg k-part roped in place + kbf bf16 (NOT scaled).
__global__ __launch_bounds__(256) void rope_all(
    const float* __restrict__ q, float* __restrict__ kvg,
    ushort* __restrict__ qbf, ushort* __restrict__ kbf) {
  const int t = blockIdx.x;
  const float lnb_over = 9.210340371976184f / 32.f;  // ln(10000)/32
  const float QS = 0.18033688011112042f;  // 0.125 * log2(e)
  for (int job = threadIdx.x; job < (NHQ + NG) * 32; job += 256) {
    int h = job >> 5, j = job & 31;
    float inv = expf(-(float)j * lnb_over);
    float fr = (float)t * inv;
    float c_ = cosf(fr), s_ = sinf(fr);
    if (h < NHQ) {
      const float cq = c_ * QS, sq = s_ * QS;
      const float* base = q + ((size_t)t * NHQ + h) * HD;
      float x1 = base[j], x2 = base[j + 32];
      ushort* ob = qbf + ((size_t)t * NHQ + h) * HD;
      ob[j] = f2bf(x1 * cq - x2 * sq);
      ob[j + 32] = f2bf(x2 * cq + x1 * sq);
    } else {
      int g = h - NHQ;
      float* base = kvg + (size_t)t * KVGW + g * 64;
      float x1 = base[j], x2 = base[j + 32];
      float o1 = x1 * c_ - x2 * s_, o2 = x2 * c_ + x1 * s_;
      base[j] = o1; base[j + 32] = o2;
      kbf[(size_t)t * 128 + g * 64 + j] = f2bf(o1);
      kbf[(size_t)t * 128 + g * 64 + j + 32] = f2bf(o2);
    }
  }
}

// ------- compression (round-7 structure): one c per block, grid (128, 2),
// 256 thr. Wck/Wcv (2 MB fp32) are L2-resident across the 254 blocks.
// c==127 writes the zero pad row (c is padded 127 -> 128).
__global__ __launch_bounds__(256) void compress_kv(
    const float* __restrict__ kvg,
    const float* __restrict__ Wck, const float* __restrict__ Wcv,
    ushort* __restrict__ ck16, ushort* __restrict__ cvt16) {
  const int c = blockIdx.x, g = blockIdx.y;
  const int tid = threadIdx.x;
  if (c == 127) {  // zero pad so MFMA never touches garbage
    if (tid < 64) ck16[((size_t)127 * NG + g) * HD + tid] = 0;
    else if (tid < 128) cvt16[((size_t)g * HD + (tid - 64)) * 128 + 127] = 0;
    return;
  }
  const int d = tid & 63, chunk = tid >> 6;
  __shared__ float red[2][4][64];
  float ak = 0.f, av = 0.f;
  #pragma unroll 4
  for (int f = chunk * 512; f < chunk * 512 + 512; ++f) {
    int i = f >> 6, e = f & 63;
    int trow = c * CSTRIDE + i;
    float kv = kvg[(size_t)trow * KVGW + g * 64 + e];
    float vv = kvg[(size_t)trow * KVGW + 128 + g * 64 + e];
    ak += kv * Wck[((size_t)g * 2048 + f) * HD + d];
    av += vv * Wcv[((size_t)g * 2048 + f) * HD + d];
  }
  red[0][chunk][d] = ak;
  red[1][chunk][d] = av;
  __syncthreads();
  if (tid < 64) {
    ck16[((size_t)c * NG + g) * HD + tid] =
        f2bf(red[0][0][tid] + red[0][1][tid] + red[0][2][tid] + red[0][3][tid]);
  } else if (tid < 128) {
    int dd = tid - 64;
    cvt16[((size_t)g * HD + dd) * 128 + c] =
        f2bf(red[1][0][dd] + red[1][1][dd] + red[1][2][dd] + red[1][3][dd]);
  }
}

// ------- MFMA compressed attention + block scores + parallel top-16 -------
// grid (128 t-tiles of 16, 2 g), 512 threads = 8 waves x 2 heads each.
// q is log2-domain pre-scaled (rope_all) -> softmax via EXP2 (v_exp_f32).
__global__ __launch_bounds__(512) void comp_attn(
    const ushort* __restrict__ qbf, const ushort* __restrict__ ck16,
    const ushort* __restrict__ cvt16, const float* __restrict__ kvg,
    float* __restrict__ comb, unsigned* __restrict__ sel) {
  const int tb = 127 - blockIdx.x, g = blockIdx.y;  // LPT tail packing
  const int t0 = tb * 16;
  const int tid = threadIdx.x, lane = tid & 63, w = tid >> 6;
  const int quad = lane >> 4, l16 = lane & 15;
  const int qb = t0 >> 6;  // uniform across the 16 t's of this block

  __shared__ float colsum[16][129];  // [t_local][c], padded vs bank conflicts
  for (int i = tid; i < 16 * 129; i += 512) ((float*)colsum)[i] = 0.f;
  __syncthreads();

  const int t = t0 + l16;
  const int cmaxv = (t >= 31) ? min(126, (t - 31) >> 4) : -1;
  const int h0 = w * 2;  // two heads per wave

  short8_t qB[2][2];
  #pragma unroll
  for (int hh = 0; hh < 2; ++hh)
    #pragma unroll
    for (int kd = 0; kd < 2; ++kd)
      qB[hh][kd] = *(const short8_t*)(qbf +
          ((size_t)t * NHQ + g * 16 + h0 + hh) * HD + kd * 32 + quad * 8);

  const f32x4 fz = {0.f, 0.f, 0.f, 0.f};
  f32x4 sp[2][8];

  #pragma unroll
  for (int ct = 0; ct < 8; ++ct) {
    const ushort* kr = ck16 + ((size_t)(ct * 16 + l16) * NG + g) * HD + quad * 8;
    short8_t kA0 = *(const short8_t*)kr;
    short8_t kA1 = *(const short8_t*)(kr + 32);
    #pragma unroll
    for (int hh = 0; hh < 2; ++hh) {
      f32x4 c0 = __builtin_amdgcn_mfma_f32_16x16x32_bf16(kA0, qB[hh][0], fz, 0, 0, 0);
      sp[hh][ct] = __builtin_amdgcn_mfma_f32_16x16x32_bf16(kA1, qB[hh][1], c0, 0, 0, 0);
    }
  }

  short4_t pB[2][8];
  #pragma unroll
  for (int hh = 0; hh < 2; ++hh) {
    float mx = -INFINITY;
    #pragma unroll
    for (int ct = 0; ct < 8; ++ct)
      #pragma unroll
      for (int r = 0; r < 4; ++r) {
        int c = ct * 16 + quad * 4 + r;
        float s_ = (c <= cmaxv) ? sp[hh][ct][r] : -INFINITY;
        sp[hh][ct][r] = s_;
        mx = fmaxf(mx, s_);
      }
    mx = fmaxf(mx, __shfl_xor(mx, 16));
    mx = fmaxf(mx, __shfl_xor(mx, 32));
    if (mx == -INFINITY) mx = 0.f;  // fully-masked rows (t < 31)
    float ls = 0.f;
    #pragma unroll
    for (int ct = 0; ct < 8; ++ct)
      #pragma unroll
      for (int r = 0; r < 4; ++r) {
        float p = EXP2(sp[hh][ct][r] - mx);
        sp[hh][ct][r] = p;
        ls += p;
      }
    ls += __shfl_xor(ls, 16);
    ls += __shfl_xor(ls, 32);
    float inv = (ls > 0.f) ? 1.f / ls : 0.f;
    #pragma unroll
    for (int ct = 0; ct < 8; ++ct) {
      short4_t pk;
      #pragma unroll
      for (int r = 0; r < 4; ++r) {
        float pn = sp[hh][ct][r] * inv;
        sp[hh][ct][r] = pn;
        pk[r] = (short)f2bf(pn);
      }
      pB[hh][ct] = pk;
    }
  }

  #pragma unroll
  for (int ct = 0; ct < 8; ++ct)
    #pragma unroll
    for (int r = 0; r < 4; ++r)
      atomicAdd(&colsum[l16][ct * 16 + quad * 4 + r],
                sp[0][ct][r] + sp[1][ct][r]);

  f32x4 acc[2][4];
  #pragma unroll
  for (int hh = 0; hh < 2; ++hh)
    #pragma unroll
    for (int dt = 0; dt < 4; ++dt) acc[hh][dt] = fz;
  #pragma unroll
  for (int ct = 0; ct < 8; ++ct) {
    short4_t vA[4];
    #pragma unroll
    for (int dt = 0; dt < 4; ++dt)
      vA[dt] = *(const short4_t*)(cvt16 +
          ((size_t)g * HD + dt * 16 + l16) * 128 + ct * 16 + quad * 4);
    #pragma unroll
    for (int hh = 0; hh < 2; ++hh)
      #pragma unroll
      for (int dt = 0; dt < 4; ++dt)
        acc[hh][dt] = __builtin_amdgcn_mfma_f32_16x16x16bf16_1k(
            vA[dt], pB[hh][ct], acc[hh][dt], 0, 0, 0);
  }

  const float g0 = 1.f / (1.f + __expf(-kvg[(size_t)t * KVGW + 256]));
  #pragma unroll
  for (int hh = 0; hh < 2; ++hh)
    #pragma unroll
    for (int dt = 0; dt < 4; ++dt)
      #pragma unroll
      for (int r = 0; r < 4; ++r)
        comb[((size_t)t * NHQ + g * 16 + h0 + hh) * HD + dt * 16 + quad * 4 + r] =
            g0 * acc[hh][dt][r];

  __syncthreads();

  {
    const int tl = tid >> 5;   // 0..15
    const int b = tid & 31;
    float s;
    if (b > qb) s = -INFINITY;
    else if (b == 0 || qb - b < 2) s = INFINITY;
    else {
      s = 0.f;
      #pragma unroll
      for (int i = 0; i < 5; ++i) s += colsum[tl][4 * b - 1 + i];
    }
    unsigned key = (s < 0.f) ? 0u : (__float_as_uint(s) + 1u);
    unsigned msel = 0;
    for (int it = 0; it < 16; ++it) {
      unsigned long long pk =
          (((unsigned long long)key) << 6) | (unsigned)(63 - b);
      #pragma unroll
      for (int off = 16; off >= 1; off >>= 1) {
        unsigned long long o = __shfl_xor(pk, off);
        if (o > pk) pk = o;
      }
      if ((pk >> 6) == 0) break;  // uniform within the 32-group
      int bs = 63 - (int)(pk & 63);
      msel |= 1u << bs;
      if (b == bs) key = 0;
    }
    if (b == 0) sel[(size_t)(t0 + tl) * NG + g] = msel;
  }
}

// ------- MFMA flash attention v11: mode-fused + fused FINAL epilogue +
// raw v_exp_f32 softmax (EXP2 builtin) + wave-level mode-0 skip.
// grid (32 qb, 2 g, 8 hgp). (512,2): 128-VGPR cap (60 used), no spill.
__global__ __launch_bounds__(512, 2) void mfma_attn(
    const ushort* __restrict__ qb16, const ushort* __restrict__ kb16,
    const ushort* __restrict__ vtb, const float* __restrict__ kvg,
    const unsigned* __restrict__ sel, const float* __restrict__ comb1,
    ushort* __restrict__ combb) {
  const int g = blockIdx.y;
  const int hgp = blockIdx.z;
  const int qb = (hgp >= 4) ? blockIdx.x : 31 - blockIdx.x;  // pair-balance
  const int tid = threadIdx.x, lane = tid & 63, w = tid >> 6;  // 8 waves
  const int quad = lane >> 4, l16 = lane & 15;
  const int head = g * 16 + hgp * 2 + (w >> 2);
  const int t0 = qb * 64;

  __shared__ __align__(16) ushort Ks[2][64 * 64];  // 16 KB (dbuf)
  __shared__ __align__(16) ushort Vs[2][64 * 64];  // 16 KB (dbuf)
  __shared__ unsigned sel_s[64];

  if (tid < 64) sel_s[tid] = sel[(size_t)(t0 + tid) * NG + g];
  __syncthreads();

  // my 16 queries (one 16-row tile per wave)
  const int qg = t0 + (w & 3) * 16 + l16;
  const unsigned sbq = sel_s[(w & 3) * 16 + l16];

  short8_t qB0 = *(const short8_t*)(qb16 +
      ((size_t)qg * NHQ + head) * HD + quad * 8);
  short8_t qB1 = *(const short8_t*)(qb16 +
      ((size_t)qg * NHQ + head) * HD + 32 + quad * 8);

  float m0 = -1e30f, m1 = -1e30f;
  f32x4 acc0[4], acc1[4], accL0, accL1;
  const f32x4 fz = {0.f, 0.f, 0.f, 0.f};
  #pragma unroll
  for (int dt = 0; dt < 4; ++dt) { acc0[dt] = fz; acc1[dt] = fz; }
  accL0 = fz; accL1 = fz;
  const short4_t onesA = {(short)0x3F80, (short)0x3F80,
                          (short)0x3F80, (short)0x3F80};  // bf16 1.0 x4

  // block lists: sparse union (all 8 waves identical) and sliding window
  unsigned uni = sel_s[lane];
  #pragma unroll
  for (int off = 32; off >= 1; off >>= 1) uni |= __shfl_xor(uni, off);
  const int b0w = (qb > 8) ? qb - 8 : 0;
  const unsigned wmask = ((1u << (qb - b0w + 1)) - 1u) << b0w;
  unsigned lrem = uni | wmask;
  const int nb = __popc(lrem);

  // stage K (XOR 16B chunk swizzle) and V^T (linear; perm pre-baked in vtb)
  #define STAGE(buf, blk)                                                     \
    {                                                                         \
      const int blk_ = (blk);                                                 \
      const int row = tid >> 3, cl = tid & 7;                                 \
      const int kck = cl ^ (row & 7);                                         \
      glds16(kb16 + (size_t)(blk_ * 64 + row) * 128 + g * 64 + kck * 8,       \
             &Ks[buf][tid * 8]);                                              \
      glds16(vtb + ((size_t)g * 64 + row) * 2048 + blk_ * 64 + cl * 8,        \
             &Vs[buf][tid * 8]);                                              \
    }

  int blkcur = __ffs(lrem) - 1; lrem &= lrem - 1;
  STAGE(0, blkcur);
  __syncthreads();  // tile 0 resident

  const int e = l16 & 7;  // K-read perm

  for (int ib = 0; ib < nb; ++ib) {
    const int cur = ib & 1;
    const int blk = blkcur;
    if (ib + 1 < nb) {  // prefetch next tile into other buffer
      blkcur = __ffs(lrem) - 1; lrem &= lrem - 1;
      STAGE(cur ^ 1, blkcur);
    }

    // S^T = K Q^T from LDS — computed ONCE, shared by both modes
    f32x4 sp[4];
    __builtin_amdgcn_s_setprio(1);
    #pragma unroll
    for (int kt = 0; kt < 4; ++kt) {
      const ushort* kr = &Ks[cur][(kt * 16 + l16) * 64];
      short8_t kA0 = *(const short8_t*)(kr + ((quad ^ e) * 8));
      short8_t kA1 = *(const short8_t*)(kr + ((quad ^ e ^ 4) * 8));
      f32x4 c = __builtin_amdgcn_mfma_f32_16x16x32_bf16(kA0, qB0, fz, 0, 0, 0);
      sp[kt] = __builtin_amdgcn_mfma_f32_16x16x32_bf16(kA1, qB1, c, 0, 0, 0);
    }
    __builtin_amdgcn_s_setprio(0);

    const bool diag = (blk == qb);
    const bool wedge = (blk == qb - 8);           // window-edge (qb>=8 only)
    const bool inU = ((uni >> blk) & 1u) != 0;    // uniform
    const bool inW = ((wmask >> blk) & 1u) != 0;  // uniform
    const bool selq = ((sbq >> blk) & 1u) != 0;   // per-query

    // shared raw row-max (valid for all fully-unmasked cases)
    float rm = -INFINITY;
    #pragma unroll
    for (int kt = 0; kt < 4; ++kt)
      #pragma unroll
      for (int r = 0; r < 4; ++r) rm = fmaxf(rm, sp[kt][r]);
    rm = fmaxf(rm, __shfl_xor(rm, 16));
    rm = fmaxf(rm, __shfl_xor(rm, 32));

    // ---- mode 0: sparse (sel); skip if NO query in this wave selected it
    if (inU && __any(selq)) {
      float mx;
      if (!diag) {
        mx = selq ? rm : -INFINITY;
      } else {
        mx = -INFINITY;
        #pragma unroll
        for (int kt = 0; kt < 4; ++kt)
          #pragma unroll
          for (int r = 0; r < 4; ++r) {
            int key = blk * 64 + kt * 16 + quad * 4 + r;
            bool ok = selq && (key <= qg);
            mx = ok ? fmaxf(mx, sp[kt][r]) : mx;
          }
        mx = fmaxf(mx, __shfl_xor(mx, 16));
        mx = fmaxf(mx, __shfl_xor(mx, 32));
      }
      if (!__all(mx <= m0 + 11.f)) {  // T13 defer-max (log2 domain)
        float mnew = fmaxf(m0, mx);
        float alpha = EXP2(m0 - mnew);
        #pragma unroll
        for (int dt = 0; dt < 4; ++dt)
          #pragma unroll
          for (int r = 0; r < 4; ++r) acc0[dt][r] *= alpha;
        #pragma unroll
        for (int r = 0; r < 4; ++r) accL0[r] *= alpha;
        m0 = mnew;
      }
      short4_t pB[4];
      #pragma unroll
      for (int kt = 0; kt < 4; ++kt) {
        union { unsigned u[2]; short4_t s; } pk;
        if (!diag) {
          float p0 = EXP2(sp[kt][0] - m0), p1 = EXP2(sp[kt][1] - m0);
          float p2 = EXP2(sp[kt][2] - m0), p3 = EXP2(sp[kt][3] - m0);
          asm("v_cvt_pk_bf16_f32 %0, %1, %2" : "=v"(pk.u[0]) : "v"(p0), "v"(p1));
          asm("v_cvt_pk_bf16_f32 %0, %1, %2" : "=v"(pk.u[1]) : "v"(p2), "v"(p3));
          pk.u[0] = selq ? pk.u[0] : 0u;
          pk.u[1] = selq ? pk.u[1] : 0u;
        } else {
          float p[4];
          #pragma unroll
          for (int r = 0; r < 4; ++r) {
            int key = blk * 64 + kt * 16 + quad * 4 + r;
            bool ok = selq && (key <= qg);
            p[r] = ok ? EXP2(sp[kt][r] - m0) : 0.f;
          }
          asm("v_cvt_pk_bf16_f32 %0, %1, %2" : "=v"(pk.u[0]) : "v"(p[0]), "v"(p[1]));
          asm("v_cvt_pk_bf16_f32 %0, %1, %2" : "=v"(pk.u[1]) : "v"(p[2]), "v"(p[3]));
        }
        pB[kt] = pk.s;
      }
      __builtin_amdgcn_s_setprio(1);
      #pragma unroll
      for (int kt = 0; kt < 4; ++kt) {
        #pragma unroll
        for (int dt = 0; dt < 4; ++dt) {
          short4_t vA = *(const short4_t*)(&Vs[cur][(dt * 16 + l16) * 64 +
                                                    (((kt * 4 + quad) ^ l16) << 2)]);
          acc0[dt] = __builtin_amdgcn_mfma_f32_16x16x16bf16_1k(
              vA, pB[kt], acc0[dt], 0, 0, 0);
        }
        accL0 = __builtin_amdgcn_mfma_f32_16x16x16bf16_1k(
            onesA, pB[kt], accL0, 0, 0, 0);
      }
      __builtin_amdgcn_s_setprio(0);
    }

    // ---- mode 1: sliding window ----
    if (inW) {
      float mx;
      if (!diag && !wedge) {
        mx = rm;  // fully valid block
      } else {
        mx = -INFINITY;
        #pragma unroll
        for (int kt = 0; kt < 4; ++kt)
          #pragma unroll
          for (int r = 0; r < 4; ++r) {
            int key = blk * 64 + kt * 16 + quad * 4 + r;
            bool ok = (key <= qg) && (qg - key <= 512);
            mx = ok ? fmaxf(mx, sp[kt][r]) : mx;
          }
        mx = fmaxf(mx, __shfl_xor(mx, 16));
        mx = fmaxf(mx, __shfl_xor(mx, 32));
      }
      if (!__all(mx <= m1 + 11.f)) {  // T13 defer-max (log2 domain)
        float mnew = fmaxf(m1, mx);
        float alpha = EXP2(m1 - mnew);
        #pragma unroll
        for (int dt = 0; dt < 4; ++dt)
          #pragma unroll
          for (int r = 0; r < 4; ++r) acc1[dt][r] *= alpha;
        #pragma unroll
        for (int r = 0; r < 4; ++r) accL1[r] *= alpha;
        m1 = mnew;
      }
      short4_t pB[4];
      #pragma unroll
      for (int kt = 0; kt < 4; ++kt) {
        union { unsigned u[2]; short4_t s; } pk;
        if (!diag && !wedge) {
          float p0 = EXP2(sp[kt][0] - m1), p1 = EXP2(sp[kt][1] - m1);
          float p2 = EXP2(sp[kt][2] - m1), p3 = EXP2(sp[kt][3] - m1);
          asm("v_cvt_pk_bf16_f32 %0, %1, %2" : "=v"(pk.u[0]) : "v"(p0), "v"(p1));
          asm("v_cvt_pk_bf16_f32 %0, %1, %2" : "=v"(pk.u[1]) : "v"(p2), "v"(p3));
        } else {
          float p[4];
          #pragma unroll
          for (int r = 0; r < 4; ++r) {
            int key = blk * 64 + kt * 16 + quad * 4 + r;
            bool ok = (key <= qg) && (qg - key <= 512);
            p[r] = ok ? EXP2(sp[kt][r] - m1) : 0.f;
          }
          asm("v_cvt_pk_bf16_f32 %0, %1, %2" : "=v"(pk.u[0]) : "v"(p[0]), "v"(p[1]));
          asm("v_cvt_pk_bf16_f32 %0, %1, %2" : "=v"(pk.u[1]) : "v"(p[2]), "v"(p[3]));
        }
        pB[kt] = pk.s;
      }
      __builtin_amdgcn_s_setprio(1);
      #pragma unroll
      for (int kt = 0; kt < 4; ++kt) {
        #pragma unroll
        for (int dt = 0; dt < 4; ++dt) {
          short4_t vA = *(const short4_t*)(&Vs[cur][(dt * 16 + l16) * 64 +
                                                    (((kt * 4 + quad) ^ l16) << 2)]);
          acc1[dt] = __builtin_amdgcn_mfma_f32_16x16x16bf16_1k(
              vA, pB[kt], acc1[dt], 0, 0, 0);
        }
        accL1 = __builtin_amdgcn_mfma_f32_16x16x16bf16_1k(
            onesA, pB[kt], accL1, 0, 0, 0);
      }
      __builtin_amdgcn_s_setprio(0);
    }

    __syncthreads();  // all reads of buf[cur] done; next STAGE may overwrite
  }
  #undef STAGE

  // fused FINAL epilogue: combb(bf16) = comb1 + c0*sparse + c1*slide
  const float c0 =
      (1.f / (1.f + __expf(-kvg[(size_t)qg * KVGW + 257]))) / accL0[0];
  const float c1 =
      (1.f / (1.f + __expf(-kvg[(size_t)qg * KVGW + 258]))) / accL1[0];
  #pragma unroll
  for (int dt = 0; dt < 4; ++dt) {
    const size_t base = ((size_t)qg * NHQ + head) * HD + dt * 16 + quad * 4;
    f32x4 cv = *(const f32x4*)(comb1 + base);
    short4_t o;
    #pragma unroll
    for (int r = 0; r < 4; ++r)
      o[r] = (short)f2bf(cv[r] + c0 * acc0[dt][r] + c1 * acc1[dt][r]);
    *(short4_t*)(combb + base) = o;
  }
}

extern "C" void kernel_launch(void* const* d_in, const int* in_sizes, int n_in,
                              void* d_out, int out_size, void* d_ws, size_t ws_size,
                              hipStream_t stream) {
  const float* x   = (const float*)d_in[0];
  const float* Wq  = (const float*)d_in[1];
  const float* Wk  = (const float*)d_in[2];
  const float* Wv  = (const float*)d_in[3];
  const float* Wo  = (const float*)d_in[4];
  const float* Wg  = (const float*)d_in[5];
  const float* Wck = (const float*)d_in[6];
  const float* Wcv = (const float*)d_in[7];
  float* out = (float*)d_out;
  float* ws = (float*)d_ws;

  float* qbuf   = ws;                           // 4,194,304 f
  float* comb1  = qbuf + 4194304;               // 4,194,304 f
  float* kvg    = comb1 + 4194304;              //   786,432 f
  float* ckb    = kvg + 786432;                 //    16,384 f (bf16 ck+cvT)
  float* cvb    = ckb + 16384;                  //    16,384 f (unused)
  unsigned* sel = (unsigned*)(cvb + 16384);     //     4,096 u32
  ushort* kbf   = (ushort*)(sel + 4096);        //   262,144 u16
  ushort* vtb   = kbf + 262144;                 //   262,144 u16
  ushort* wkvgb = vtb + 262144;                 //   786,432 u16
  ushort* regA  = wkvgb + 786432;               // 4,194,304 u16: xb -> combb
  ushort* regB  = regA + 4194304;               // 4,194,304 u16: wqb -> qbf
  ushort* xb = regA;      ushort* combb = regA;
  ushort* wqb = regB;     ushort* qbf = regB;
  ushort* wob = (ushort*)qbuf;        // fp32 q dead after rope_all

  ushort* ckb16 = (ushort*)ckb;       // 128*2*64 u16 = 32 KB
  ushort* cvtb  = ckb16 + 16384;      // 2*64*128 u16 = 32 KB (within ckb slot)

  const int CV4 = (1048576 + 255) / 256;  // 4M elems / 4 per thread
  cvt_bf<<<CV4, 256, 0, stream>>>(x, xb, 4194304);
  cvt_bf<<<CV4, 256, 0, stream>>>(Wq, wqb, 4194304);
  pack_wkvg<<<(KVGW * 2048 + 255) / 256, 256, 0, stream>>>(Wk, Wv, Wg, wkvgb);

  mgemm<<<dim3(32, 16), 512, 0, stream>>>(xb, wqb, qbuf, 2048, 2048, 2048);
  mgemm<<<dim3(6, 16), 512, 0, stream>>>(xb, wkvgb, kvg, 2048, KVGW, 2048);

  rope_all<<<2048, 256, 0, stream>>>(qbuf, kvg, qbf, kbf);
  cvt_bf<<<CV4, 256, 0, stream>>>(Wo, wob, 4194304);  // qbuf free after rope
  cvt_vt<<<(262144 + 255) / 256, 256, 0, stream>>>(kvg, vtb);
  compress_kv<<<dim3(128, 2), 256, 0, stream>>>(kvg, Wck, Wcv, ckb16, cvtb);
  comp_attn<<<dim3(128, 2), 512, 0, stream>>>(qbf, ckb16, cvtb, kvg, comb1, sel);
  mfma_attn<<<dim3(32, 2, 8), 512, 0, stream>>>(qbf, kbf, vtb, kvg, sel, comb1, combb);

  mgemm<<<dim3(32, 16), 512, 0, stream>>>(combb, wob, out, 2048, 2048, 2048);
}

// Round 17
// 357.633 us; speedup vs baseline: 1.0213x; 1.0213x over previous
//
#include <hip/hip_runtime.h>
#include <math.h>

#define T_SEQ 2048
#define NHQ 32
#define NG 2
#define HD 64
#define CSTRIDE 16
#define KVGW 384  // fused k|v|gate row width: 128 k + 128 v + 3 gate + pad

// raw v_exp_f32 (computes 2^x). HIP's exp2f() is the PRECISE ocml version
// (~6 extra VALU ops: round-14 VALUBusy 37->50% regression); __expf is
// v_mul(log2e)+v_exp. The builtin is the single-instruction path.
#if defined(__has_builtin)
#if __has_builtin(__builtin_amdgcn_exp2f)
#define EXP2(x) __builtin_amdgcn_exp2f(x)
#endif
#endif
#ifndef EXP2
#define EXP2(x) __expf(0.6931471805599453f * (x))
#endif

typedef __attribute__((ext_vector_type(8))) short short8_t;
typedef __attribute__((ext_vector_type(4))) short short4_t;
typedef __attribute__((ext_vector_type(4))) float f32x4;

__device__ __forceinline__ ushort f2bf(float x) {  // round-to-nearest-even
  union { float f; unsigned u; } c; c.f = x;
  unsigned r = c.u + 0x7fff + ((c.u >> 16) & 1);
  return (ushort)(r >> 16);
}
__device__ __forceinline__ float bf2f(ushort u) {
  union { unsigned u; float f; } c; c.u = ((unsigned)u) << 16;
  return c.f;
}

__device__ __forceinline__ void glds16(const ushort* g, ushort* l) {
  __builtin_amdgcn_global_load_lds(
      (const __attribute__((address_space(1))) unsigned int*)g,
      (__attribute__((address_space(3))) unsigned int*)l, 16, 0, 0);
}

// ---- bf16 MFMA GEMM: C[M,N] = A[M,K] * B[N,K]^T (m97 recipe + XOR swizzle)
// BM=128 x BN=64 tile, 256 thr = 4 waves (wave tile 64x32): at N=2048 grid
// 32x16 = 512 wgs = 2 wg/CU -> independent barriers overlap vmcnt drains.
// MEASURED BEST (round 15: 351.8us wall). Round-16's 8-wave 32x32 variant
// REGRESSED +13us: halves per-wave ILP (4 indep MFMAs/kt vs 8) and the
// extra waves just contend on the same MFMA pipe. Keep 4 waves.
__global__ __launch_bounds__(256) void mgemm(
    const ushort* __restrict__ A, const ushort* __restrict__ B,
    float* __restrict__ C, int M, int N, int K) {
  __shared__ __align__(16) ushort As[128 * 64];
  __shared__ __align__(16) ushort Bs[64 * 64];
  const int tid = threadIdx.x;
  const int lane = tid & 63, w = tid >> 6;  // 4 waves
  const int quad = lane >> 4, l16 = lane & 15;
  const int m0 = blockIdx.y * 128, n0 = blockIdx.x * 64;
  const int mq = (w & 1) * 64, nq = (w >> 1) * 32;
  f32x4 acc[4][2];
  const f32x4 fz = {0.f, 0.f, 0.f, 0.f};
  #pragma unroll
  for (int i = 0; i < 4; ++i)
    #pragma unroll
    for (int j = 0; j < 2; ++j) acc[i][j] = fz;

  for (int k0 = 0; k0 < K; k0 += 64) {
    __syncthreads();
    #pragma unroll
    for (int j = 0; j < 4; ++j) {  // A: 128 rows x 8 chunks
      int ci = j * 256 + tid;
      int row = ci >> 3, cl = ci & 7;
      int kc = cl ^ (row & 7);
      glds16(A + ((size_t)(m0 + row) * K + k0 + kc * 8), &As[ci * 8]);
    }
    #pragma unroll
    for (int j = 0; j < 2; ++j) {  // B: 64 rows x 8 chunks
      int ci = j * 256 + tid;
      int row = ci >> 3, cl = ci & 7;
      int kc = cl ^ (row & 7);
      glds16(B + ((size_t)(n0 + row) * K + k0 + kc * 8), &Bs[ci * 8]);
    }
    __syncthreads();
    #pragma unroll
    for (int kt = 0; kt < 2; ++kt) {
      short8_t af[4], bf_[2];
      #pragma unroll
      for (int mt = 0; mt < 4; ++mt) {
        int row = mq + mt * 16 + l16;
        int cl = (kt * 4 + quad) ^ (row & 7);
        af[mt] = *(const short8_t*)&As[row * 64 + cl * 8];
      }
      #pragma unroll
      for (int nt = 0; nt < 2; ++nt) {
        int row = nq + nt * 16 + l16;
        int cl = (kt * 4 + quad) ^ (row & 7);
        bf_[nt] = *(const short8_t*)&Bs[row * 64 + cl * 8];
      }
      #pragma unroll
      for (int mt = 0; mt < 4; ++mt)
        #pragma unroll
        for (int nt = 0; nt < 2; ++nt)
          acc[mt][nt] = __builtin_amdgcn_mfma_f32_16x16x32_bf16(
              af[mt], bf_[nt], acc[mt][nt], 0, 0, 0);
    }
  }
  #pragma unroll
  for (int mt = 0; mt < 4; ++mt)
    #pragma unroll
    for (int nt = 0; nt < 2; ++nt)
      #pragma unroll
      for (int r = 0; r < 4; ++r) {
        int m = m0 + mq + mt * 16 + quad * 4 + r;
        int n = n0 + nq + nt * 16 + l16;
        C[(size_t)m * N + n] = acc[mt][nt][r];
      }
}

// ---------------- conversions / packing (float4-vectorized, G13) ----------
__global__ __launch_bounds__(256) void cvt_bf(const float* __restrict__ src,
                                              ushort* __restrict__ dst, int n) {
  int i = (blockIdx.x * 256 + threadIdx.x) * 4;
  if (i >= n) return;
  float4 v = *(const float4*)(src + i);
  short4_t o = {(short)f2bf(v.x), (short)f2bf(v.y),
                (short)f2bf(v.z), (short)f2bf(v.w)};
  *(short4_t*)(dst + i) = o;
}

__global__ __launch_bounds__(256) void pack_wkvg(
    const float* __restrict__ Wk, const float* __restrict__ Wv,
    const float* __restrict__ Wg, ushort* __restrict__ dst) {
  int i = blockIdx.x * 256 + threadIdx.x;
  if (i >= KVGW * 2048) return;
  int n = i >> 11, k = i & 2047;
  float v;
  if (n < 128) v = Wk[(size_t)n * 2048 + k];
  else if (n < 256) v = Wv[(size_t)(n - 128) * 2048 + k];
  else if (n < 259) v = Wg[(size_t)(n - 256) * 2048 + k];
  else v = 0.f;
  dst[i] = f2bf(v);
}

// vt[g][d][*] bf16 from kvg v-part (v is NOT roped), with an 8B-slot
// permutation baked into each 64-key block: key k of block blk is stored at
// blk*64 + ((k>>2)^(d&15))*4 + (k&3). mfma_attn stages rows LINEARLY and
// reads slot (kt*4+quad)^l16 -> conflict-free b64 phases (verified r7: 6.39M->0).
__global__ __launch_bounds__(256) void cvt_vt(const float* __restrict__ kvg,
                                              ushort* __restrict__ vt) {
  int i = blockIdx.x * 256 + threadIdx.x;
  if (i >= T_SEQ * NG * HD) return;
  int d = i & 63, g = (i >> 6) & 1, s = i >> 7;
  int blk = s >> 6, k = s & 63;
  int snew = blk * 64 + (((k >> 2) ^ (d & 15)) << 2) + (k & 3);
  vt[((size_t)g * HD + d) * T_SEQ + snew] =
      f2bf(kvg[(size_t)s * KVGW + 128 + g * 64 + d]);
}

// ------- RoPE: q fp32 -> qbf bf16 PRE-SCALED by 0.125*log2(e) so attention
// scores are in the log2 domain: softmax uses raw v_exp_f32 (EXP2) with no
// per-element log2e multiply. Softmax is base-invariant after normalization.
// kvg k-part roped in place + kbf bf16 (NOT scaled).
__global__ __launch_bounds__(256) void rope_all(
    const float* __restrict__ q, float* __restrict__ kvg,
    ushort* __restrict__ qbf, ushort* __restrict__ kbf) {
  const int t = blockIdx.x;
  const float lnb_over = 9.210340371976184f / 32.f;  // ln(10000)/32
  const float QS = 0.18033688011112042f;  // 0.125 * log2(e)
  for (int job = threadIdx.x; job < (NHQ + NG) * 32; job += 256) {
    int h = job >> 5, j = job & 31;
    float inv = expf(-(float)j * lnb_over);
    float fr = (float)t * inv;
    float c_ = cosf(fr), s_ = sinf(fr);
    if (h < NHQ) {
      const float cq = c_ * QS, sq = s_ * QS;
      const float* base = q + ((size_t)t * NHQ + h) * HD;
      float x1 = base[j], x2 = base[j + 32];
      ushort* ob = qbf + ((size_t)t * NHQ + h) * HD;
      ob[j] = f2bf(x1 * cq - x2 * sq);
      ob[j + 32] = f2bf(x2 * cq + x1 * sq);
    } else {
      int g = h - NHQ;
      float* base = kvg + (size_t)t * KVGW + g * 64;
      float x1 = base[j], x2 = base[j + 32];
      float o1 = x1 * c_ - x2 * s_, o2 = x2 * c_ + x1 * s_;
      base[j] = o1; base[j + 32] = o2;
      kbf[(size_t)t * 128 + g * 64 + j] = f2bf(o1);
      kbf[(size_t)t * 128 + g * 64 + j + 32] = f2bf(o2);
    }
  }
}

// ------- compression (round-7 structure): one c per block, grid (128, 2),
// 256 thr. Wck/Wcv (2 MB fp32) are L2-resident across the 254 blocks.
// c==127 writes the zero pad row (c is padded 127 -> 128).
__global__ __launch_bounds__(256) void compress_kv(
    const float* __restrict__ kvg,
    const float* __restrict__ Wck, const float* __restrict__ Wcv,
    ushort* __restrict__ ck16, ushort* __restrict__ cvt16) {
  const int c = blockIdx.x, g = blockIdx.y;
  const int tid = threadIdx.x;
  if (c == 127) {  // zero pad so MFMA never touches garbage
    if (tid < 64) ck16[((size_t)127 * NG + g) * HD + tid] = 0;
    else if (tid < 128) cvt16[((size_t)g * HD + (tid - 64)) * 128 + 127] = 0;
    return;
  }
  const int d = tid & 63, chunk = tid >> 6;
  __shared__ float red[2][4][64];
  float ak = 0.f, av = 0.f;
  #pragma unroll 4
  for (int f = chunk * 512; f < chunk * 512 + 512; ++f) {
    int i = f >> 6, e = f & 63;
    int trow = c * CSTRIDE + i;
    float kv = kvg[(size_t)trow * KVGW + g * 64 + e];
    float vv = kvg[(size_t)trow * KVGW + 128 + g * 64 + e];
    ak += kv * Wck[((size_t)g * 2048 + f) * HD + d];
    av += vv * Wcv[((size_t)g * 2048 + f) * HD + d];
  }
  red[0][chunk][d] = ak;
  red[1][chunk][d] = av;
  __syncthreads();
  if (tid < 64) {
    ck16[((size_t)c * NG + g) * HD + tid] =
        f2bf(red[0][0][tid] + red[0][1][tid] + red[0][2][tid] + red[0][3][tid]);
  } else if (tid < 128) {
    int dd = tid - 64;
    cvt16[((size_t)g * HD + dd) * 128 + c] =
        f2bf(red[1][0][dd] + red[1][1][dd] + red[1][2][dd] + red[1][3][dd]);
  }
}

// ------- MFMA compressed attention + block scores + parallel top-16 -------
// grid (128 t-tiles of 16, 2 g), 512 threads = 8 waves x 2 heads each.
// q is log2-domain pre-scaled (rope_all) -> softmax via EXP2 (v_exp_f32).
__global__ __launch_bounds__(512) void comp_attn(
    const ushort* __restrict__ qbf, const ushort* __restrict__ ck16,
    const ushort* __restrict__ cvt16, const float* __restrict__ kvg,
    float* __restrict__ comb, unsigned* __restrict__ sel) {
  const int tb = 127 - blockIdx.x, g = blockIdx.y;  // LPT tail packing
  const int t0 = tb * 16;
  const int tid = threadIdx.x, lane = tid & 63, w = tid >> 6;
  const int quad = lane >> 4, l16 = lane & 15;
  const int qb = t0 >> 6;  // uniform across the 16 t's of this block

  __shared__ float colsum[16][129];  // [t_local][c], padded vs bank conflicts
  for (int i = tid; i < 16 * 129; i += 512) ((float*)colsum)[i] = 0.f;
  __syncthreads();

  const int t = t0 + l16;
  const int cmaxv = (t >= 31) ? min(126, (t - 31) >> 4) : -1;
  const int h0 = w * 2;  // two heads per wave

  short8_t qB[2][2];
  #pragma unroll
  for (int hh = 0; hh < 2; ++hh)
    #pragma unroll
    for (int kd = 0; kd < 2; ++kd)
      qB[hh][kd] = *(const short8_t*)(qbf +
          ((size_t)t * NHQ + g * 16 + h0 + hh) * HD + kd * 32 + quad * 8);

  const f32x4 fz = {0.f, 0.f, 0.f, 0.f};
  f32x4 sp[2][8];

  #pragma unroll
  for (int ct = 0; ct < 8; ++ct) {
    const ushort* kr = ck16 + ((size_t)(ct * 16 + l16) * NG + g) * HD + quad * 8;
    short8_t kA0 = *(const short8_t*)kr;
    short8_t kA1 = *(const short8_t*)(kr + 32);
    #pragma unroll
    for (int hh = 0; hh < 2; ++hh) {
      f32x4 c0 = __builtin_amdgcn_mfma_f32_16x16x32_bf16(kA0, qB[hh][0], fz, 0, 0, 0);
      sp[hh][ct] = __builtin_amdgcn_mfma_f32_16x16x32_bf16(kA1, qB[hh][1], c0, 0, 0, 0);
    }
  }

  short4_t pB[2][8];
  #pragma unroll
  for (int hh = 0; hh < 2; ++hh) {
    float mx = -INFINITY;
    #pragma unroll
    for (int ct = 0; ct < 8; ++ct)
      #pragma unroll
      for (int r = 0; r < 4; ++r) {
        int c = ct * 16 + quad * 4 + r;
        float s_ = (c <= cmaxv) ? sp[hh][ct][r] : -INFINITY;
        sp[hh][ct][r] = s_;
        mx = fmaxf(mx, s_);
      }
    mx = fmaxf(mx, __shfl_xor(mx, 16));
    mx = fmaxf(mx, __shfl_xor(mx, 32));
    if (mx == -INFINITY) mx = 0.f;  // fully-masked rows (t < 31)
    float ls = 0.f;
    #pragma unroll
    for (int ct = 0; ct < 8; ++ct)
      #pragma unroll
      for (int r = 0; r < 4; ++r) {
        float p = EXP2(sp[hh][ct][r] - mx);
        sp[hh][ct][r] = p;
        ls += p;
      }
    ls += __shfl_xor(ls, 16);
    ls += __shfl_xor(ls, 32);
    float inv = (ls > 0.f) ? 1.f / ls : 0.f;
    #pragma unroll
    for (int ct = 0; ct < 8; ++ct) {
      short4_t pk;
      #pragma unroll
      for (int r = 0; r < 4; ++r) {
        float pn = sp[hh][ct][r] * inv;
        sp[hh][ct][r] = pn;
        pk[r] = (short)f2bf(pn);
      }
      pB[hh][ct] = pk;
    }
  }

  #pragma unroll
  for (int ct = 0; ct < 8; ++ct)
    #pragma unroll
    for (int r = 0; r < 4; ++r)
      atomicAdd(&colsum[l16][ct * 16 + quad * 4 + r],
                sp[0][ct][r] + sp[1][ct][r]);

  f32x4 acc[2][4];
  #pragma unroll
  for (int hh = 0; hh < 2; ++hh)
    #pragma unroll
    for (int dt = 0; dt < 4; ++dt) acc[hh][dt] = fz;
  #pragma unroll
  for (int ct = 0; ct < 8; ++ct) {
    short4_t vA[4];
    #pragma unroll
    for (int dt = 0; dt < 4; ++dt)
      vA[dt] = *(const short4_t*)(cvt16 +
          ((size_t)g * HD + dt * 16 + l16) * 128 + ct * 16 + quad * 4);
    #pragma unroll
    for (int hh = 0; hh < 2; ++hh)
      #pragma unroll
      for (int dt = 0; dt < 4; ++dt)
        acc[hh][dt] = __builtin_amdgcn_mfma_f32_16x16x16bf16_1k(
            vA[dt], pB[hh][ct], acc[hh][dt], 0, 0, 0);
  }

  const float g0 = 1.f / (1.f + __expf(-kvg[(size_t)t * KVGW + 256]));
  #pragma unroll
  for (int hh = 0; hh < 2; ++hh)
    #pragma unroll
    for (int dt = 0; dt < 4; ++dt)
      #pragma unroll
      for (int r = 0; r < 4; ++r)
        comb[((size_t)t * NHQ + g * 16 + h0 + hh) * HD + dt * 16 + quad * 4 + r] =
            g0 * acc[hh][dt][r];

  __syncthreads();

  {
    const int tl = tid >> 5;   // 0..15
    const int b = tid & 31;
    float s;
    if (b > qb) s = -INFINITY;
    else if (b == 0 || qb - b < 2) s = INFINITY;
    else {
      s = 0.f;
      #pragma unroll
      for (int i = 0; i < 5; ++i) s += colsum[tl][4 * b - 1 + i];
    }
    unsigned key = (s < 0.f) ? 0u : (__float_as_uint(s) + 1u);
    unsigned msel = 0;
    for (int it = 0; it < 16; ++it) {
      unsigned long long pk =
          (((unsigned long long)key) << 6) | (unsigned)(63 - b);
      #pragma unroll
      for (int off = 16; off >= 1; off >>= 1) {
        unsigned long long o = __shfl_xor(pk, off);
        if (o > pk) pk = o;
      }
      if ((pk >> 6) == 0) break;  // uniform within the 32-group
      int bs = 63 - (int)(pk & 63);
      msel |= 1u << bs;
      if (b == bs) key = 0;
    }
    if (b == 0) sel[(size_t)(t0 + tl) * NG + g] = msel;
  }
}

// ------- MFMA flash attention v11: mode-fused + fused FINAL epilogue +
// raw v_exp_f32 softmax (EXP2 builtin) + wave-level mode-0 skip.
// grid (32 qb, 2 g, 8 hgp). (512,2): 128-VGPR cap (60 used), no spill.
__global__ __launch_bounds__(512, 2) void mfma_attn(
    const ushort* __restrict__ qb16, const ushort* __restrict__ kb16,
    const ushort* __restrict__ vtb, const float* __restrict__ kvg,
    const unsigned* __restrict__ sel, const float* __restrict__ comb1,
    ushort* __restrict__ combb) {
  const int g = blockIdx.y;
  const int hgp = blockIdx.z;
  const int qb = (hgp >= 4) ? blockIdx.x : 31 - blockIdx.x;  // pair-balance
  const int tid = threadIdx.x, lane = tid & 63, w = tid >> 6;  // 8 waves
  const int quad = lane >> 4, l16 = lane & 15;
  const int head = g * 16 + hgp * 2 + (w >> 2);
  const int t0 = qb * 64;

  __shared__ __align__(16) ushort Ks[2][64 * 64];  // 16 KB (dbuf)
  __shared__ __align__(16) ushort Vs[2][64 * 64];  // 16 KB (dbuf)
  __shared__ unsigned sel_s[64];

  if (tid < 64) sel_s[tid] = sel[(size_t)(t0 + tid) * NG + g];
  __syncthreads();

  // my 16 queries (one 16-row tile per wave)
  const int qg = t0 + (w & 3) * 16 + l16;
  const unsigned sbq = sel_s[(w & 3) * 16 + l16];

  short8_t qB0 = *(const short8_t*)(qb16 +
      ((size_t)qg * NHQ + head) * HD + quad * 8);
  short8_t qB1 = *(const short8_t*)(qb16 +
      ((size_t)qg * NHQ + head) * HD + 32 + quad * 8);

  float m0 = -1e30f, m1 = -1e30f;
  f32x4 acc0[4], acc1[4], accL0, accL1;
  const f32x4 fz = {0.f, 0.f, 0.f, 0.f};
  #pragma unroll
  for (int dt = 0; dt < 4; ++dt) { acc0[dt] = fz; acc1[dt] = fz; }
  accL0 = fz; accL1 = fz;
  const short4_t onesA = {(short)0x3F80, (short)0x3F80,
                          (short)0x3F80, (short)0x3F80};  // bf16 1.0 x4

  // block lists: sparse union (all 8 waves identical) and sliding window
  unsigned uni = sel_s[lane];
  #pragma unroll
  for (int off = 32; off >= 1; off >>= 1) uni |= __shfl_xor(uni, off);
  const int b0w = (qb > 8) ? qb - 8 : 0;
  const unsigned wmask = ((1u << (qb - b0w + 1)) - 1u) << b0w;
  unsigned lrem = uni | wmask;
  const int nb = __popc(lrem);

  // stage K (XOR 16B chunk swizzle) and V^T (linear; perm pre-baked in vtb)
  #define STAGE(buf, blk)                                                     \
    {                                                                         \
      const int blk_ = (blk);                                                 \
      const int row = tid >> 3, cl = tid & 7;                                 \
      const int kck = cl ^ (row & 7);                                         \
      glds16(kb16 + (size_t)(blk_ * 64 + row) * 128 + g * 64 + kck * 8,       \
             &Ks[buf][tid * 8]);                                              \
      glds16(vtb + ((size_t)g * 64 + row) * 2048 + blk_ * 64 + cl * 8,        \
             &Vs[buf][tid * 8]);                                              \
    }

  int blkcur = __ffs(lrem) - 1; lrem &= lrem - 1;
  STAGE(0, blkcur);
  __syncthreads();  // tile 0 resident

  const int e = l16 & 7;  // K-read perm

  for (int ib = 0; ib < nb; ++ib) {
    const int cur = ib & 1;
    const int blk = blkcur;
    if (ib + 1 < nb) {  // prefetch next tile into other buffer
      blkcur = __ffs(lrem) - 1; lrem &= lrem - 1;
      STAGE(cur ^ 1, blkcur);
    }

    // S^T = K Q^T from LDS — computed ONCE, shared by both modes
    f32x4 sp[4];
    __builtin_amdgcn_s_setprio(1);
    #pragma unroll
    for (int kt = 0; kt < 4; ++kt) {
      const ushort* kr = &Ks[cur][(kt * 16 + l16) * 64];
      short8_t kA0 = *(const short8_t*)(kr + ((quad ^ e) * 8));
      short8_t kA1 = *(const short8_t*)(kr + ((quad ^ e ^ 4) * 8));
      f32x4 c = __builtin_amdgcn_mfma_f32_16x16x32_bf16(kA0, qB0, fz, 0, 0, 0);
      sp[kt] = __builtin_amdgcn_mfma_f32_16x16x32_bf16(kA1, qB1, c, 0, 0, 0);
    }
    __builtin_amdgcn_s_setprio(0);

    const bool diag = (blk == qb);
    const bool wedge = (blk == qb - 8);           // window-edge (qb>=8 only)
    const bool inU = ((uni >> blk) & 1u) != 0;    // uniform
    const bool inW = ((wmask >> blk) & 1u) != 0;  // uniform
    const bool selq = ((sbq >> blk) & 1u) != 0;   // per-query

    // shared raw row-max (valid for all fully-unmasked cases)
    float rm = -INFINITY;
    #pragma unroll
    for (int kt = 0; kt < 4; ++kt)
      #pragma unroll
      for (int r = 0; r < 4; ++r) rm = fmaxf(rm, sp[kt][r]);
    rm = fmaxf(rm, __shfl_xor(rm, 16));
    rm = fmaxf(rm, __shfl_xor(rm, 32));

    // ---- mode 0: sparse (sel); skip if NO query in this wave selected it
    if (inU && __any(selq)) {
      float mx;
      if (!diag) {
        mx = selq ? rm : -INFINITY;
      } else {
        mx = -INFINITY;
        #pragma unroll
        for (int kt = 0; kt < 4; ++kt)
          #pragma unroll
          for (int r = 0; r < 4; ++r) {
            int key = blk * 64 + kt * 16 + quad * 4 + r;
            bool ok = selq && (key <= qg);
            mx = ok ? fmaxf(mx, sp[kt][r]) : mx;
          }
        mx = fmaxf(mx, __shfl_xor(mx, 16));
        mx = fmaxf(mx, __shfl_xor(mx, 32));
      }
      if (!__all(mx <= m0 + 11.f)) {  // T13 defer-max (log2 domain)
        float mnew = fmaxf(m0, mx);
        float alpha = EXP2(m0 - mnew);
        #pragma unroll
        for (int dt = 0; dt < 4; ++dt)
          #pragma unroll
          for (int r = 0; r < 4; ++r) acc0[dt][r] *= alpha;
        #pragma unroll
        for (int r = 0; r < 4; ++r) accL0[r] *= alpha;
        m0 = mnew;
      }
      short4_t pB[4];
      #pragma unroll
      for (int kt = 0; kt < 4; ++kt) {
        union { unsigned u[2]; short4_t s; } pk;
        if (!diag) {
          float p0 = EXP2(sp[kt][0] - m0), p1 = EXP2(sp[kt][1] - m0);
          float p2 = EXP2(sp[kt][2] - m0), p3 = EXP2(sp[kt][3] - m0);
          asm("v_cvt_pk_bf16_f32 %0, %1, %2" : "=v"(pk.u[0]) : "v"(p0), "v"(p1));
          asm("v_cvt_pk_bf16_f32 %0, %1, %2" : "=v"(pk.u[1]) : "v"(p2), "v"(p3));
          pk.u[0] = selq ? pk.u[0] : 0u;
          pk.u[1] = selq ? pk.u[1] : 0u;
        } else {
          float p[4];
          #pragma unroll
          for (int r = 0; r < 4; ++r) {
            int key = blk * 64 + kt * 16 + quad * 4 + r;
            bool ok = selq && (key <= qg);
            p[r] = ok ? EXP2(sp[kt][r] - m0) : 0.f;
          }
          asm("v_cvt_pk_bf16_f32 %0, %1, %2" : "=v"(pk.u[0]) : "v"(p[0]), "v"(p[1]));
          asm("v_cvt_pk_bf16_f32 %0, %1, %2" : "=v"(pk.u[1]) : "v"(p[2]), "v"(p[3]));
        }
        pB[kt] = pk.s;
      }
      __builtin_amdgcn_s_setprio(1);
      #pragma unroll
      for (int kt = 0; kt < 4; ++kt) {
        #pragma unroll
        for (int dt = 0; dt < 4; ++dt) {
          short4_t vA = *(const short4_t*)(&Vs[cur][(dt * 16 + l16) * 64 +
                                                    (((kt * 4 + quad) ^ l16) << 2)]);
          acc0[dt] = __builtin_amdgcn_mfma_f32_16x16x16bf16_1k(
              vA, pB[kt], acc0[dt], 0, 0, 0);
        }
        accL0 = __builtin_amdgcn_mfma_f32_16x16x16bf16_1k(
            onesA, pB[kt], accL0, 0, 0, 0);
      }
      __builtin_amdgcn_s_setprio(0);
    }

    // ---- mode 1: sliding window ----
    if (inW) {
      float mx;
      if (!diag && !wedge) {
        mx = rm;  // fully valid block
      } else {
        mx = -INFINITY;
        #pragma unroll
        for (int kt = 0; kt < 4; ++kt)
          #pragma unroll
          for (int r = 0; r < 4; ++r) {
            int key = blk * 64 + kt * 16 + quad * 4 + r;
            bool ok = (key <= qg) && (qg - key <= 512);
            mx = ok ? fmaxf(mx, sp[kt][r]) : mx;
          }
        mx = fmaxf(mx, __shfl_xor(mx, 16));
        mx = fmaxf(mx, __shfl_xor(mx, 32));
      }
      if (!__all(mx <= m1 + 11.f)) {  // T13 defer-max (log2 domain)
        float mnew = fmaxf(m1, mx);
        float alpha = EXP2(m1 - mnew);
        #pragma unroll
        for (int dt = 0; dt < 4; ++dt)
          #pragma unroll
          for (int r = 0; r < 4; ++r) acc1[dt][r] *= alpha;
        #pragma unroll
        for (int r = 0; r < 4; ++r) accL1[r] *= alpha;
        m1 = mnew;
      }
      short4_t pB[4];
      #pragma unroll
      for (int kt = 0; kt < 4; ++kt) {
        union { unsigned u[2]; short4_t s; } pk;
        if (!diag && !wedge) {
          float p0 = EXP2(sp[kt][0] - m1), p1 = EXP2(sp[kt][1] - m1);
          float p2 = EXP2(sp[kt][2] - m1), p3 = EXP2(sp[kt][3] - m1);
          asm("v_cvt_pk_bf16_f32 %0, %1, %2" : "=v"(pk.u[0]) : "v"(p0), "v"(p1));
          asm("v_cvt_pk_bf16_f32 %0, %1, %2" : "=v"(pk.u[1]) : "v"(p2), "v"(p3));
        } else {
          float p[4];
          #pragma unroll
          for (int r = 0; r < 4; ++r) {
            int key = blk * 64 + kt * 16 + quad * 4 + r;
            bool ok = (key <= qg) && (qg - key <= 512);
            p[r] = ok ? EXP2(sp[kt][r] - m1) : 0.f;
          }
          asm("v_cvt_pk_bf16_f32 %0, %1, %2" : "=v"(pk.u[0]) : "v"(p[0]), "v"(p[1]));
          asm("v_cvt_pk_bf16_f32 %0, %1, %2" : "=v"(pk.u[1]) : "v"(p[2]), "v"(p[3]));
        }
        pB[kt] = pk.s;
      }
      __builtin_amdgcn_s_setprio(1);
      #pragma unroll
      for (int kt = 0; kt < 4; ++kt) {
        #pragma unroll
        for (int dt = 0; dt < 4; ++dt) {
          short4_t vA = *(const short4_t*)(&Vs[cur][(dt * 16 + l16) * 64 +
                                                    (((kt * 4 + quad) ^ l16) << 2)]);
          acc1[dt] = __builtin_amdgcn_mfma_f32_16x16x16bf16_1k(
              vA, pB[kt], acc1[dt], 0, 0, 0);
        }
        accL1 = __builtin_amdgcn_mfma_f32_16x16x16bf16_1k(
            onesA, pB[kt], accL1, 0, 0, 0);
      }
      __builtin_amdgcn_s_setprio(0);
    }

    __syncthreads();  // all reads of buf[cur] done; next STAGE may overwrite
  }
  #undef STAGE

  // fused FINAL epilogue: combb(bf16) = comb1 + c0*sparse + c1*slide
  const float c0 =
      (1.f / (1.f + __expf(-kvg[(size_t)qg * KVGW + 257]))) / accL0[0];
  const float c1 =
      (1.f / (1.f + __expf(-kvg[(size_t)qg * KVGW + 258]))) / accL1[0];
  #pragma unroll
  for (int dt = 0; dt < 4; ++dt) {
    const size_t base = ((size_t)qg * NHQ + head) * HD + dt * 16 + quad * 4;
    f32x4 cv = *(const f32x4*)(comb1 + base);
    short4_t o;
    #pragma unroll
    for (int r = 0; r < 4; ++r)
      o[r] = (short)f2bf(cv[r] + c0 * acc0[dt][r] + c1 * acc1[dt][r]);
    *(short4_t*)(combb + base) = o;
  }
}

extern "C" void kernel_launch(void* const* d_in, const int* in_sizes, int n_in,
                              void* d_out, int out_size, void* d_ws, size_t ws_size,
                              hipStream_t stream) {
  const float* x   = (const float*)d_in[0];
  const float* Wq  = (const float*)d_in[1];
  const float* Wk  = (const float*)d_in[2];
  const float* Wv  = (const float*)d_in[3];
  const float* Wo  = (const float*)d_in[4];
  const float* Wg  = (const float*)d_in[5];
  const float* Wck = (const float*)d_in[6];
  const float* Wcv = (const float*)d_in[7];
  float* out = (float*)d_out;
  float* ws = (float*)d_ws;

  float* qbuf   = ws;                           // 4,194,304 f
  float* comb1  = qbuf + 4194304;               // 4,194,304 f
  float* kvg    = comb1 + 4194304;              //   786,432 f
  float* ckb    = kvg + 786432;                 //    16,384 f (bf16 ck+cvT)
  float* cvb    = ckb + 16384;                  //    16,384 f (unused)
  unsigned* sel = (unsigned*)(cvb + 16384);     //     4,096 u32
  ushort* kbf   = (ushort*)(sel + 4096);        //   262,144 u16
  ushort* vtb   = kbf + 262144;                 //   262,144 u16
  ushort* wkvgb = vtb + 262144;                 //   786,432 u16
  ushort* regA  = wkvgb + 786432;               // 4,194,304 u16: xb -> combb
  ushort* regB  = regA + 4194304;               // 4,194,304 u16: wqb -> qbf
  ushort* xb = regA;      ushort* combb = regA;
  ushort* wqb = regB;     ushort* qbf = regB;
  ushort* wob = (ushort*)qbuf;        // fp32 q dead after rope_all

  ushort* ckb16 = (ushort*)ckb;       // 128*2*64 u16 = 32 KB
  ushort* cvtb  = ckb16 + 16384;      // 2*64*128 u16 = 32 KB (within ckb slot)

  const int CV4 = (1048576 + 255) / 256;  // 4M elems / 4 per thread
  cvt_bf<<<CV4, 256, 0, stream>>>(x, xb, 4194304);
  cvt_bf<<<CV4, 256, 0, stream>>>(Wq, wqb, 4194304);
  pack_wkvg<<<(KVGW * 2048 + 255) / 256, 256, 0, stream>>>(Wk, Wv, Wg, wkvgb);

  mgemm<<<dim3(32, 16), 256, 0, stream>>>(xb, wqb, qbuf, 2048, 2048, 2048);
  mgemm<<<dim3(6, 16), 256, 0, stream>>>(xb, wkvgb, kvg, 2048, KVGW, 2048);

  rope_all<<<2048, 256, 0, stream>>>(qbuf, kvg, qbf, kbf);
  cvt_bf<<<CV4, 256, 0, stream>>>(Wo, wob, 4194304);  // qbuf free after rope
  cvt_vt<<<(262144 + 255) / 256, 256, 0, stream>>>(kvg, vtb);
  compress_kv<<<dim3(128, 2), 256, 0, stream>>>(kvg, Wck, Wcv, ckb16, cvtb);
  comp_attn<<<dim3(128, 2), 512, 0, stream>>>(qbf, ckb16, cvtb, kvg, comb1, sel);
  mfma_attn<<<dim3(32, 2, 8), 512, 0, stream>>>(qbf, kbf, vtb, kvg, sel, comb1, combb);

  mgemm<<<dim3(32, 16), 256, 0, stream>>>(combb, wob, out, 2048, 2048, 2048);
}

// Round 18
// 352.630 us; speedup vs baseline: 1.0358x; 1.0142x over previous
//
#include <hip/hip_runtime.h>
#include <math.h>

#define T_SEQ 2048
#define NHQ 32
#define NG 2
#define HD 64
#define CSTRIDE 16
#define KVGW 384  // fused k|v|gate row width: 128 k + 128 v + 3 gate + pad

// raw v_exp_f32 (computes 2^x). HIP's exp2f() is the PRECISE ocml version
// (~6 extra VALU ops: round-14 VALUBusy 37->50% regression); __expf is
// v_mul(log2e)+v_exp. The builtin is the single-instruction path.
#if defined(__has_builtin)
#if __has_builtin(__builtin_amdgcn_exp2f)
#define EXP2(x) __builtin_amdgcn_exp2f(x)
#endif
#endif
#ifndef EXP2
#define EXP2(x) __expf(0.6931471805599453f * (x))
#endif

typedef __attribute__((ext_vector_type(8))) short short8_t;
typedef __attribute__((ext_vector_type(4))) short short4_t;
typedef __attribute__((ext_vector_type(4))) float f32x4;

__device__ __forceinline__ ushort f2bf(float x) {  // round-to-nearest-even
  union { float f; unsigned u; } c; c.f = x;
  unsigned r = c.u + 0x7fff + ((c.u >> 16) & 1);
  return (ushort)(r >> 16);
}
__device__ __forceinline__ float bf2f(ushort u) {
  union { unsigned u; float f; } c; c.u = ((unsigned)u) << 16;
  return c.f;
}

__device__ __forceinline__ void glds16(const ushort* g, ushort* l) {
  __builtin_amdgcn_global_load_lds(
      (const __attribute__((address_space(1))) unsigned int*)g,
      (__attribute__((address_space(3))) unsigned int*)l, 16, 0, 0);
}

// ---- bf16 MFMA GEMM: C[M,N] = A[M,K] * B[N,K]^T (m97 recipe + XOR swizzle)
// BM=128 x BN=64 tile, 256 thr = 4 waves (wave tile 64x32): at N=2048 grid
// 32x16 = 512 wgs = 2 wg/CU -> independent barriers overlap vmcnt drains.
// MEASURED BEST (round 15/17). 8-wave 32x32 variant regressed +13us (r16).
__global__ __launch_bounds__(256) void mgemm(
    const ushort* __restrict__ A, const ushort* __restrict__ B,
    float* __restrict__ C, int M, int N, int K) {
  __shared__ __align__(16) ushort As[128 * 64];
  __shared__ __align__(16) ushort Bs[64 * 64];
  const int tid = threadIdx.x;
  const int lane = tid & 63, w = tid >> 6;  // 4 waves
  const int quad = lane >> 4, l16 = lane & 15;
  const int m0 = blockIdx.y * 128, n0 = blockIdx.x * 64;
  const int mq = (w & 1) * 64, nq = (w >> 1) * 32;
  f32x4 acc[4][2];
  const f32x4 fz = {0.f, 0.f, 0.f, 0.f};
  #pragma unroll
  for (int i = 0; i < 4; ++i)
    #pragma unroll
    for (int j = 0; j < 2; ++j) acc[i][j] = fz;

  for (int k0 = 0; k0 < K; k0 += 64) {
    __syncthreads();
    #pragma unroll
    for (int j = 0; j < 4; ++j) {  // A: 128 rows x 8 chunks
      int ci = j * 256 + tid;
      int row = ci >> 3, cl = ci & 7;
      int kc = cl ^ (row & 7);
      glds16(A + ((size_t)(m0 + row) * K + k0 + kc * 8), &As[ci * 8]);
    }
    #pragma unroll
    for (int j = 0; j < 2; ++j) {  // B: 64 rows x 8 chunks
      int ci = j * 256 + tid;
      int row = ci >> 3, cl = ci & 7;
      int kc = cl ^ (row & 7);
      glds16(B + ((size_t)(n0 + row) * K + k0 + kc * 8), &Bs[ci * 8]);
    }
    __syncthreads();
    #pragma unroll
    for (int kt = 0; kt < 2; ++kt) {
      short8_t af[4], bf_[2];
      #pragma unroll
      for (int mt = 0; mt < 4; ++mt) {
        int row = mq + mt * 16 + l16;
        int cl = (kt * 4 + quad) ^ (row & 7);
        af[mt] = *(const short8_t*)&As[row * 64 + cl * 8];
      }
      #pragma unroll
      for (int nt = 0; nt < 2; ++nt) {
        int row = nq + nt * 16 + l16;
        int cl = (kt * 4 + quad) ^ (row & 7);
        bf_[nt] = *(const short8_t*)&Bs[row * 64 + cl * 8];
      }
      #pragma unroll
      for (int mt = 0; mt < 4; ++mt)
        #pragma unroll
        for (int nt = 0; nt < 2; ++nt)
          acc[mt][nt] = __builtin_amdgcn_mfma_f32_16x16x32_bf16(
              af[mt], bf_[nt], acc[mt][nt], 0, 0, 0);
    }
  }
  #pragma unroll
  for (int mt = 0; mt < 4; ++mt)
    #pragma unroll
    for (int nt = 0; nt < 2; ++nt)
      #pragma unroll
      for (int r = 0; r < 4; ++r) {
        int m = m0 + mq + mt * 16 + quad * 4 + r;
        int n = n0 + nq + nt * 16 + l16;
        C[(size_t)m * N + n] = acc[mt][nt][r];
      }
}

// ---- K-split mgemm: grid (N/64, M/128, 4); z computes K-quarter partial
// into Cp + z*M*N. For the kvg GEMM (N=384): 96 wgs -> 384 wgs (was 0.37
// wg/CU with 160 CUs idle and full barrier-drain exposure); makespan ~1/4.
__global__ __launch_bounds__(256) void mgemm_ks(
    const ushort* __restrict__ A, const ushort* __restrict__ B,
    float* __restrict__ Cp, int M, int N, int K) {
  __shared__ __align__(16) ushort As[128 * 64];
  __shared__ __align__(16) ushort Bs[64 * 64];
  const int tid = threadIdx.x;
  const int lane = tid & 63, w = tid >> 6;  // 4 waves
  const int quad = lane >> 4, l16 = lane & 15;
  const int m0 = blockIdx.y * 128, n0 = blockIdx.x * 64;
  const int mq = (w & 1) * 64, nq = (w >> 1) * 32;
  const int kq = K >> 2;
  const int kbeg = blockIdx.z * kq, kend = kbeg + kq;
  float* C = Cp + (size_t)blockIdx.z * M * N;
  f32x4 acc[4][2];
  const f32x4 fz = {0.f, 0.f, 0.f, 0.f};
  #pragma unroll
  for (int i = 0; i < 4; ++i)
    #pragma unroll
    for (int j = 0; j < 2; ++j) acc[i][j] = fz;

  for (int k0 = kbeg; k0 < kend; k0 += 64) {
    __syncthreads();
    #pragma unroll
    for (int j = 0; j < 4; ++j) {  // A: 128 rows x 8 chunks
      int ci = j * 256 + tid;
      int row = ci >> 3, cl = ci & 7;
      int kc = cl ^ (row & 7);
      glds16(A + ((size_t)(m0 + row) * K + k0 + kc * 8), &As[ci * 8]);
    }
    #pragma unroll
    for (int j = 0; j < 2; ++j) {  // B: 64 rows x 8 chunks
      int ci = j * 256 + tid;
      int row = ci >> 3, cl = ci & 7;
      int kc = cl ^ (row & 7);
      glds16(B + ((size_t)(n0 + row) * K + k0 + kc * 8), &Bs[ci * 8]);
    }
    __syncthreads();
    #pragma unroll
    for (int kt = 0; kt < 2; ++kt) {
      short8_t af[4], bf_[2];
      #pragma unroll
      for (int mt = 0; mt < 4; ++mt) {
        int row = mq + mt * 16 + l16;
        int cl = (kt * 4 + quad) ^ (row & 7);
        af[mt] = *(const short8_t*)&As[row * 64 + cl * 8];
      }
      #pragma unroll
      for (int nt = 0; nt < 2; ++nt) {
        int row = nq + nt * 16 + l16;
        int cl = (kt * 4 + quad) ^ (row & 7);
        bf_[nt] = *(const short8_t*)&Bs[row * 64 + cl * 8];
      }
      #pragma unroll
      for (int mt = 0; mt < 4; ++mt)
        #pragma unroll
        for (int nt = 0; nt < 2; ++nt)
          acc[mt][nt] = __builtin_amdgcn_mfma_f32_16x16x32_bf16(
              af[mt], bf_[nt], acc[mt][nt], 0, 0, 0);
    }
  }
  #pragma unroll
  for (int mt = 0; mt < 4; ++mt)
    #pragma unroll
    for (int nt = 0; nt < 2; ++nt)
      #pragma unroll
      for (int r = 0; r < 4; ++r) {
        int m = m0 + mq + mt * 16 + quad * 4 + r;
        int n = n0 + nq + nt * 16 + l16;
        C[(size_t)m * N + n] = acc[mt][nt][r];
      }
}

// sum of 4 K-partials (float4-vectorized)
__global__ __launch_bounds__(256) void sum4(const float* __restrict__ p,
                                            float* __restrict__ dst, int n) {
  int i = (blockIdx.x * 256 + threadIdx.x) * 4;
  if (i >= n) return;
  float4 a = *(const float4*)(p + i);
  float4 b = *(const float4*)(p + n + i);
  float4 c = *(const float4*)(p + 2 * (size_t)n + i);
  float4 d = *(const float4*)(p + 3 * (size_t)n + i);
  float4 o = {a.x + b.x + c.x + d.x, a.y + b.y + c.y + d.y,
              a.z + b.z + c.z + d.z, a.w + b.w + c.w + d.w};
  *(float4*)(dst + i) = o;
}

// ---------------- conversions / packing (float4-vectorized, G13) ----------
__global__ __launch_bounds__(256) void cvt_bf(const float* __restrict__ src,
                                              ushort* __restrict__ dst, int n) {
  int i = (blockIdx.x * 256 + threadIdx.x) * 4;
  if (i >= n) return;
  float4 v = *(const float4*)(src + i);
  short4_t o = {(short)f2bf(v.x), (short)f2bf(v.y),
                (short)f2bf(v.z), (short)f2bf(v.w)};
  *(short4_t*)(dst + i) = o;
}

__global__ __launch_bounds__(256) void pack_wkvg(
    const float* __restrict__ Wk, const float* __restrict__ Wv,
    const float* __restrict__ Wg, ushort* __restrict__ dst) {
  int i = blockIdx.x * 256 + threadIdx.x;
  if (i >= KVGW * 2048) return;
  int n = i >> 11, k = i & 2047;
  float v;
  if (n < 128) v = Wk[(size_t)n * 2048 + k];
  else if (n < 256) v = Wv[(size_t)(n - 128) * 2048 + k];
  else if (n < 259) v = Wg[(size_t)(n - 256) * 2048 + k];
  else v = 0.f;
  dst[i] = f2bf(v);
}

// vt[g][d][*] bf16 from kvg v-part (v is NOT roped), with an 8B-slot
// permutation baked into each 64-key block: key k of block blk is stored at
// blk*64 + ((k>>2)^(d&15))*4 + (k&3). mfma_attn stages rows LINEARLY and
// reads slot (kt*4+quad)^l16 -> conflict-free b64 phases (verified r7: 6.39M->0).
__global__ __launch_bounds__(256) void cvt_vt(const float* __restrict__ kvg,
                                              ushort* __restrict__ vt) {
  int i = blockIdx.x * 256 + threadIdx.x;
  if (i >= T_SEQ * NG * HD) return;
  int d = i & 63, g = (i >> 6) & 1, s = i >> 7;
  int blk = s >> 6, k = s & 63;
  int snew = blk * 64 + (((k >> 2) ^ (d & 15)) << 2) + (k & 3);
  vt[((size_t)g * HD + d) * T_SEQ + snew] =
      f2bf(kvg[(size_t)s * KVGW + 128 + g * 64 + d]);
}

// ------- RoPE: q fp32 -> qbf bf16 PRE-SCALED by 0.125*log2(e) so attention
// scores are in the log2 domain: softmax uses raw v_exp_f32 (EXP2) with no
// per-element log2e multiply. Softmax is base-invariant after normalization.
// kvg k-part roped in place + kbf bf16 (NOT scaled).
__global__ __launch_bounds__(256) void rope_all(
    const float* __restrict__ q, float* __restrict__ kvg,
    ushort* __restrict__ qbf, ushort* __restrict__ kbf) {
  const int t = blockIdx.x;
  const float lnb_over = 9.210340371976184f / 32.f;  // ln(10000)/32
  const float QS = 0.18033688011112042f;  // 0.125 * log2(e)
  for (int job = threadIdx.x; job < (NHQ + NG) * 32; job += 256) {
    int h = job >> 5, j = job & 31;
    float inv = expf(-(float)j * lnb_over);
    float fr = (float)t * inv;
    float c_ = cosf(fr), s_ = sinf(fr);
    if (h < NHQ) {
      const float cq = c_ * QS, sq = s_ * QS;
      const float* base = q + ((size_t)t * NHQ + h) * HD;
      float x1 = base[j], x2 = base[j + 32];
      ushort* ob = qbf + ((size_t)t * NHQ + h) * HD;
      ob[j] = f2bf(x1 * cq - x2 * sq);
      ob[j + 32] = f2bf(x2 * cq + x1 * sq);
    } else {
      int g = h - NHQ;
      float* base = kvg + (size_t)t * KVGW + g * 64;
      float x1 = base[j], x2 = base[j + 32];
      float o1 = x1 * c_ - x2 * s_, o2 = x2 * c_ + x1 * s_;
      base[j] = o1; base[j + 32] = o2;
      kbf[(size_t)t * 128 + g * 64 + j] = f2bf(o1);
      kbf[(size_t)t * 128 + g * 64 + j + 32] = f2bf(o2);
    }
  }
}

// ------- compression (round-7 structure): one c per block, grid (128, 2),
// 256 thr. Wck/Wcv (2 MB fp32) are L2-resident across the 254 blocks.
// c==127 writes the zero pad row (c is padded 127 -> 128).
__global__ __launch_bounds__(256) void compress_kv(
    const float* __restrict__ kvg,
    const float* __restrict__ Wck, const float* __restrict__ Wcv,
    ushort* __restrict__ ck16, ushort* __restrict__ cvt16) {
  const int c = blockIdx.x, g = blockIdx.y;
  const int tid = threadIdx.x;
  if (c == 127) {  // zero pad so MFMA never touches garbage
    if (tid < 64) ck16[((size_t)127 * NG + g) * HD + tid] = 0;
    else if (tid < 128) cvt16[((size_t)g * HD + (tid - 64)) * 128 + 127] = 0;
    return;
  }
  const int d = tid & 63, chunk = tid >> 6;
  __shared__ float red[2][4][64];
  float ak = 0.f, av = 0.f;
  #pragma unroll 4
  for (int f = chunk * 512; f < chunk * 512 + 512; ++f) {
    int i = f >> 6, e = f & 63;
    int trow = c * CSTRIDE + i;
    float kv = kvg[(size_t)trow * KVGW + g * 64 + e];
    float vv = kvg[(size_t)trow * KVGW + 128 + g * 64 + e];
    ak += kv * Wck[((size_t)g * 2048 + f) * HD + d];
    av += vv * Wcv[((size_t)g * 2048 + f) * HD + d];
  }
  red[0][chunk][d] = ak;
  red[1][chunk][d] = av;
  __syncthreads();
  if (tid < 64) {
    ck16[((size_t)c * NG + g) * HD + tid] =
        f2bf(red[0][0][tid] + red[0][1][tid] + red[0][2][tid] + red[0][3][tid]);
  } else if (tid < 128) {
    int dd = tid - 64;
    cvt16[((size_t)g * HD + dd) * 128 + c] =
        f2bf(red[1][0][dd] + red[1][1][dd] + red[1][2][dd] + red[1][3][dd]);
  }
}

// ------- MFMA compressed attention + block scores + parallel top-16 -------
// grid (128 t-tiles of 16, 2 g), 512 threads = 8 waves x 2 heads each.
// ct-skip: only c-tiles <= ctmax = (t0-16)>>8 are causally reachable
// (uniform per block; mean 4.5/8) -> wave-uniform branch skips ~44% of
// the QK/PV MFMAs and softmax exp work. Skipped tiles contribute p=0,
// matching the previous masked-softmax semantics exactly.
__global__ __launch_bounds__(512) void comp_attn(
    const ushort* __restrict__ qbf, const ushort* __restrict__ ck16,
    const ushort* __restrict__ cvt16, const float* __restrict__ kvg,
    float* __restrict__ comb, unsigned* __restrict__ sel) {
  const int tb = 127 - blockIdx.x, g = blockIdx.y;  // LPT tail packing
  const int t0 = tb * 16;
  const int tid = threadIdx.x, lane = tid & 63, w = tid >> 6;
  const int quad = lane >> 4, l16 = lane & 15;
  const int qb = t0 >> 6;  // uniform across the 16 t's of this block
  const int ctmax = (t0 >= 16) ? ((t0 - 16) >> 8) : -1;  // last live c-tile

  __shared__ float colsum[16][129];  // [t_local][c], padded vs bank conflicts
  for (int i = tid; i < 16 * 129; i += 512) ((float*)colsum)[i] = 0.f;
  __syncthreads();

  const int t = t0 + l16;
  const int cmaxv = (t >= 31) ? min(126, (t - 31) >> 4) : -1;
  const int h0 = w * 2;  // two heads per wave

  short8_t qB[2][2];
  #pragma unroll
  for (int hh = 0; hh < 2; ++hh)
    #pragma unroll
    for (int kd = 0; kd < 2; ++kd)
      qB[hh][kd] = *(const short8_t*)(qbf +
          ((size_t)t * NHQ + g * 16 + h0 + hh) * HD + kd * 32 + quad * 8);

  const f32x4 fz = {0.f, 0.f, 0.f, 0.f};
  f32x4 sp[2][8];

  #pragma unroll
  for (int ct = 0; ct < 8; ++ct) {
    if (ct <= ctmax) {
      const ushort* kr = ck16 + ((size_t)(ct * 16 + l16) * NG + g) * HD + quad * 8;
      short8_t kA0 = *(const short8_t*)kr;
      short8_t kA1 = *(const short8_t*)(kr + 32);
      #pragma unroll
      for (int hh = 0; hh < 2; ++hh) {
        f32x4 c0 = __builtin_amdgcn_mfma_f32_16x16x32_bf16(kA0, qB[hh][0], fz, 0, 0, 0);
        sp[hh][ct] = __builtin_amdgcn_mfma_f32_16x16x32_bf16(kA1, qB[hh][1], c0, 0, 0, 0);
      }
    }
  }

  short4_t pB[2][8];
  #pragma unroll
  for (int hh = 0; hh < 2; ++hh) {
    float mx = -INFINITY;
    #pragma unroll
    for (int ct = 0; ct < 8; ++ct) {
      if (ct <= ctmax) {
        #pragma unroll
        for (int r = 0; r < 4; ++r) {
          int c = ct * 16 + quad * 4 + r;
          float s_ = (c <= cmaxv) ? sp[hh][ct][r] : -INFINITY;
          sp[hh][ct][r] = s_;
          mx = fmaxf(mx, s_);
        }
      }
    }
    mx = fmaxf(mx, __shfl_xor(mx, 16));
    mx = fmaxf(mx, __shfl_xor(mx, 32));
    if (mx == -INFINITY) mx = 0.f;  // fully-masked rows (t < 31)
    float ls = 0.f;
    #pragma unroll
    for (int ct = 0; ct < 8; ++ct) {
      if (ct <= ctmax) {
        #pragma unroll
        for (int r = 0; r < 4; ++r) {
          float p = EXP2(sp[hh][ct][r] - mx);
          sp[hh][ct][r] = p;
          ls += p;
        }
      }
    }
    ls += __shfl_xor(ls, 16);
    ls += __shfl_xor(ls, 32);
    float inv = (ls > 0.f) ? 1.f / ls : 0.f;
    #pragma unroll
    for (int ct = 0; ct < 8; ++ct) {
      if (ct <= ctmax) {
        short4_t pk;
        #pragma unroll
        for (int r = 0; r < 4; ++r) {
          float pn = sp[hh][ct][r] * inv;
          sp[hh][ct][r] = pn;
          pk[r] = (short)f2bf(pn);
        }
        pB[hh][ct] = pk;
      }
    }
  }

  #pragma unroll
  for (int ct = 0; ct < 8; ++ct) {
    if (ct <= ctmax) {
      #pragma unroll
      for (int r = 0; r < 4; ++r)
        atomicAdd(&colsum[l16][ct * 16 + quad * 4 + r],
                  sp[0][ct][r] + sp[1][ct][r]);
    }
  }

  f32x4 acc[2][4];
  #pragma unroll
  for (int hh = 0; hh < 2; ++hh)
    #pragma unroll
    for (int dt = 0; dt < 4; ++dt) acc[hh][dt] = fz;
  #pragma unroll
  for (int ct = 0; ct < 8; ++ct) {
    if (ct <= ctmax) {
      short4_t vA[4];
      #pragma unroll
      for (int dt = 0; dt < 4; ++dt)
        vA[dt] = *(const short4_t*)(cvt16 +
            ((size_t)g * HD + dt * 16 + l16) * 128 + ct * 16 + quad * 4);
      #pragma unroll
      for (int hh = 0; hh < 2; ++hh)
        #pragma unroll
        for (int dt = 0; dt < 4; ++dt)
          acc[hh][dt] = __builtin_amdgcn_mfma_f32_16x16x16bf16_1k(
              vA[dt], pB[hh][ct], acc[hh][dt], 0, 0, 0);
    }
  }

  const float g0 = 1.f / (1.f + __expf(-kvg[(size_t)t * KVGW + 256]));
  #pragma unroll
  for (int hh = 0; hh < 2; ++hh)
    #pragma unroll
    for (int dt = 0; dt < 4; ++dt)
      #pragma unroll
      for (int r = 0; r < 4; ++r)
        comb[((size_t)t * NHQ + g * 16 + h0 + hh) * HD + dt * 16 + quad * 4 + r] =
            g0 * acc[hh][dt][r];

  __syncthreads();

  {
    const int tl = tid >> 5;   // 0..15
    const int b = tid & 31;
    float s;
    if (b > qb) s = -INFINITY;
    else if (b == 0 || qb - b < 2) s = INFINITY;
    else {
      s = 0.f;
      #pragma unroll
      for (int i = 0; i < 5; ++i) s += colsum[tl][4 * b - 1 + i];
    }
    unsigned key = (s < 0.f) ? 0u : (__float_as_uint(s) + 1u);
    unsigned msel = 0;
    for (int it = 0; it < 16; ++it) {
      unsigned long long pk =
          (((unsigned long long)key) << 6) | (unsigned)(63 - b);
      #pragma unroll
      for (int off = 16; off >= 1; off >>= 1) {
        unsigned long long o = __shfl_xor(pk, off);
        if (o > pk) pk = o;
      }
      if ((pk >> 6) == 0) break;  // uniform within the 32-group
      int bs = 63 - (int)(pk & 63);
      msel |= 1u << bs;
      if (b == bs) key = 0;
    }
    if (b == 0) sel[(size_t)(t0 + tl) * NG + g] = msel;
  }
}

// ------- MFMA flash attention v11: mode-fused + fused FINAL epilogue +
// raw v_exp_f32 softmax (EXP2 builtin) + wave-level mode-0 skip.
// grid (32 qb, 2 g, 8 hgp). (512,2): 128-VGPR cap (60 used), no spill.
__global__ __launch_bounds__(512, 2) void mfma_attn(
    const ushort* __restrict__ qb16, const ushort* __restrict__ kb16,
    const ushort* __restrict__ vtb, const float* __restrict__ kvg,
    const unsigned* __restrict__ sel, const float* __restrict__ comb1,
    ushort* __restrict__ combb) {
  const int g = blockIdx.y;
  const int hgp = blockIdx.z;
  const int qb = (hgp >= 4) ? blockIdx.x : 31 - blockIdx.x;  // pair-balance
  const int tid = threadIdx.x, lane = tid & 63, w = tid >> 6;  // 8 waves
  const int quad = lane >> 4, l16 = lane & 15;
  const int head = g * 16 + hgp * 2 + (w >> 2);
  const int t0 = qb * 64;

  __shared__ __align__(16) ushort Ks[2][64 * 64];  // 16 KB (dbuf)
  __shared__ __align__(16) ushort Vs[2][64 * 64];  // 16 KB (dbuf)
  __shared__ unsigned sel_s[64];

  if (tid < 64) sel_s[tid] = sel[(size_t)(t0 + tid) * NG + g];
  __syncthreads();

  // my 16 queries (one 16-row tile per wave)
  const int qg = t0 + (w & 3) * 16 + l16;
  const unsigned sbq = sel_s[(w & 3) * 16 + l16];

  short8_t qB0 = *(const short8_t*)(qb16 +
      ((size_t)qg * NHQ + head) * HD + quad * 8);
  short8_t qB1 = *(const short8_t*)(qb16 +
      ((size_t)qg * NHQ + head) * HD + 32 + quad * 8);

  float m0 = -1e30f, m1 = -1e30f;
  f32x4 acc0[4], acc1[4], accL0, accL1;
  const f32x4 fz = {0.f, 0.f, 0.f, 0.f};
  #pragma unroll
  for (int dt = 0; dt < 4; ++dt) { acc0[dt] = fz; acc1[dt] = fz; }
  accL0 = fz; accL1 = fz;
  const short4_t onesA = {(short)0x3F80, (short)0x3F80,
                          (short)0x3F80, (short)0x3F80};  // bf16 1.0 x4

  // block lists: sparse union (all 8 waves identical) and sliding window
  unsigned uni = sel_s[lane];
  #pragma unroll
  for (int off = 32; off >= 1; off >>= 1) uni |= __shfl_xor(uni, off);
  const int b0w = (qb > 8) ? qb - 8 : 0;
  const unsigned wmask = ((1u << (qb - b0w + 1)) - 1u) << b0w;
  unsigned lrem = uni | wmask;
  const int nb = __popc(lrem);

  // stage K (XOR 16B chunk swizzle) and V^T (linear; perm pre-baked in vtb)
  #define STAGE(buf, blk)                                                     \
    {                                                                         \
      const int blk_ = (blk);                                                 \
      const int row = tid >> 3, cl = tid & 7;                                 \
      const int kck = cl ^ (row & 7);                                         \
      glds16(kb16 + (size_t)(blk_ * 64 + row) * 128 + g * 64 + kck * 8,       \
             &Ks[buf][tid * 8]);                                              \
      glds16(vtb + ((size_t)g * 64 + row) * 2048 + blk_ * 64 + cl * 8,        \
             &Vs[buf][tid * 8]);                                              \
    }

  int blkcur = __ffs(lrem) - 1; lrem &= lrem - 1;
  STAGE(0, blkcur);
  __syncthreads();  // tile 0 resident

  const int e = l16 & 7;  // K-read perm

  for (int ib = 0; ib < nb; ++ib) {
    const int cur = ib & 1;
    const int blk = blkcur;
    if (ib + 1 < nb) {  // prefetch next tile into other buffer
      blkcur = __ffs(lrem) - 1; lrem &= lrem - 1;
      STAGE(cur ^ 1, blkcur);
    }

    // S^T = K Q^T from LDS — computed ONCE, shared by both modes
    f32x4 sp[4];
    __builtin_amdgcn_s_setprio(1);
    #pragma unroll
    for (int kt = 0; kt < 4; ++kt) {
      const ushort* kr = &Ks[cur][(kt * 16 + l16) * 64];
      short8_t kA0 = *(const short8_t*)(kr + ((quad ^ e) * 8));
      short8_t kA1 = *(const short8_t*)(kr + ((quad ^ e ^ 4) * 8));
      f32x4 c = __builtin_amdgcn_mfma_f32_16x16x32_bf16(kA0, qB0, fz, 0, 0, 0);
      sp[kt] = __builtin_amdgcn_mfma_f32_16x16x32_bf16(kA1, qB1, c, 0, 0, 0);
    }
    __builtin_amdgcn_s_setprio(0);

    const bool diag = (blk == qb);
    const bool wedge = (blk == qb - 8);           // window-edge (qb>=8 only)
    const bool inU = ((uni >> blk) & 1u) != 0;    // uniform
    const bool inW = ((wmask >> blk) & 1u) != 0;  // uniform
    const bool selq = ((sbq >> blk) & 1u) != 0;   // per-query

    // shared raw row-max (valid for all fully-unmasked cases)
    float rm = -INFINITY;
    #pragma unroll
    for (int kt = 0; kt < 4; ++kt)
      #pragma unroll
      for (int r = 0; r < 4; ++r) rm = fmaxf(rm, sp[kt][r]);
    rm = fmaxf(rm, __shfl_xor(rm, 16));
    rm = fmaxf(rm, __shfl_xor(rm, 32));

    // ---- mode 0: sparse (sel); skip if NO query in this wave selected it
    if (inU && __any(selq)) {
      float mx;
      if (!diag) {
        mx = selq ? rm : -INFINITY;
      } else {
        mx = -INFINITY;
        #pragma unroll
        for (int kt = 0; kt < 4; ++kt)
          #pragma unroll
          for (int r = 0; r < 4; ++r) {
            int key = blk * 64 + kt * 16 + quad * 4 + r;
            bool ok = selq && (key <= qg);
            mx = ok ? fmaxf(mx, sp[kt][r]) : mx;
          }
        mx = fmaxf(mx, __shfl_xor(mx, 16));
        mx = fmaxf(mx, __shfl_xor(mx, 32));
      }
      if (!__all(mx <= m0 + 11.f)) {  // T13 defer-max (log2 domain)
        float mnew = fmaxf(m0, mx);
        float alpha = EXP2(m0 - mnew);
        #pragma unroll
        for (int dt = 0; dt < 4; ++dt)
          #pragma unroll
          for (int r = 0; r < 4; ++r) acc0[dt][r] *= alpha;
        #pragma unroll
        for (int r = 0; r < 4; ++r) accL0[r] *= alpha;
        m0 = mnew;
      }
      short4_t pB[4];
      #pragma unroll
      for (int kt = 0; kt < 4; ++kt) {
        union { unsigned u[2]; short4_t s; } pk;
        if (!diag) {
          float p0 = EXP2(sp[kt][0] - m0), p1 = EXP2(sp[kt][1] - m0);
          float p2 = EXP2(sp[kt][2] - m0), p3 = EXP2(sp[kt][3] - m0);
          asm("v_cvt_pk_bf16_f32 %0, %1, %2" : "=v"(pk.u[0]) : "v"(p0), "v"(p1));
          asm("v_cvt_pk_bf16_f32 %0, %1, %2" : "=v"(pk.u[1]) : "v"(p2), "v"(p3));
          pk.u[0] = selq ? pk.u[0] : 0u;
          pk.u[1] = selq ? pk.u[1] : 0u;
        } else {
          float p[4];
          #pragma unroll
          for (int r = 0; r < 4; ++r) {
            int key = blk * 64 + kt * 16 + quad * 4 + r;
            bool ok = selq && (key <= qg);
            p[r] = ok ? EXP2(sp[kt][r] - m0) : 0.f;
          }
          asm("v_cvt_pk_bf16_f32 %0, %1, %2" : "=v"(pk.u[0]) : "v"(p[0]), "v"(p[1]));
          asm("v_cvt_pk_bf16_f32 %0, %1, %2" : "=v"(pk.u[1]) : "v"(p[2]), "v"(p[3]));
        }
        pB[kt] = pk.s;
      }
      __builtin_amdgcn_s_setprio(1);
      #pragma unroll
      for (int kt = 0; kt < 4; ++kt) {
        #pragma unroll
        for (int dt = 0; dt < 4; ++dt) {
          short4_t vA = *(const short4_t*)(&Vs[cur][(dt * 16 + l16) * 64 +
                                                    (((kt * 4 + quad) ^ l16) << 2)]);
          acc0[dt] = __builtin_amdgcn_mfma_f32_16x16x16bf16_1k(
              vA, pB[kt], acc0[dt], 0, 0, 0);
        }
        accL0 = __builtin_amdgcn_mfma_f32_16x16x16bf16_1k(
            onesA, pB[kt], accL0, 0, 0, 0);
      }
      __builtin_amdgcn_s_setprio(0);
    }

    // ---- mode 1: sliding window ----
    if (inW) {
      float mx;
      if (!diag && !wedge) {
        mx = rm;  // fully valid block
      } else {
        mx = -INFINITY;
        #pragma unroll
        for (int kt = 0; kt < 4; ++kt)
          #pragma unroll
          for (int r = 0; r < 4; ++r) {
            int key = blk * 64 + kt * 16 + quad * 4 + r;
            bool ok = (key <= qg) && (qg - key <= 512);
            mx = ok ? fmaxf(mx, sp[kt][r]) : mx;
          }
        mx = fmaxf(mx, __shfl_xor(mx, 16));
        mx = fmaxf(mx, __shfl_xor(mx, 32));
      }
      if (!__all(mx <= m1 + 11.f)) {  // T13 defer-max (log2 domain)
        float mnew = fmaxf(m1, mx);
        float alpha = EXP2(m1 - mnew);
        #pragma unroll
        for (int dt = 0; dt < 4; ++dt)
          #pragma unroll
          for (int r = 0; r < 4; ++r) acc1[dt][r] *= alpha;
        #pragma unroll
        for (int r = 0; r < 4; ++r) accL1[r] *= alpha;
        m1 = mnew;
      }
      short4_t pB[4];
      #pragma unroll
      for (int kt = 0; kt < 4; ++kt) {
        union { unsigned u[2]; short4_t s; } pk;
        if (!diag && !wedge) {
          float p0 = EXP2(sp[kt][0] - m1), p1 = EXP2(sp[kt][1] - m1);
          float p2 = EXP2(sp[kt][2] - m1), p3 = EXP2(sp[kt][3] - m1);
          asm("v_cvt_pk_bf16_f32 %0, %1, %2" : "=v"(pk.u[0]) : "v"(p0), "v"(p1));
          asm("v_cvt_pk_bf16_f32 %0, %1, %2" : "=v"(pk.u[1]) : "v"(p2), "v"(p3));
        } else {
          float p[4];
          #pragma unroll
          for (int r = 0; r < 4; ++r) {
            int key = blk * 64 + kt * 16 + quad * 4 + r;
            bool ok = (key <= qg) && (qg - key <= 512);
            p[r] = ok ? EXP2(sp[kt][r] - m1) : 0.f;
          }
          asm("v_cvt_pk_bf16_f32 %0, %1, %2" : "=v"(pk.u[0]) : "v"(p[0]), "v"(p[1]));
          asm("v_cvt_pk_bf16_f32 %0, %1, %2" : "=v"(pk.u[1]) : "v"(p[2]), "v"(p[3]));
        }
        pB[kt] = pk.s;
      }
      __builtin_amdgcn_s_setprio(1);
      #pragma unroll
      for (int kt = 0; kt < 4; ++kt) {
        #pragma unroll
        for (int dt = 0; dt < 4; ++dt) {
          short4_t vA = *(const short4_t*)(&Vs[cur][(dt * 16 + l16) * 64 +
                                                    (((kt * 4 + quad) ^ l16) << 2)]);
          acc1[dt] = __builtin_amdgcn_mfma_f32_16x16x16bf16_1k(
              vA, pB[kt], acc1[dt], 0, 0, 0);
        }
        accL1 = __builtin_amdgcn_mfma_f32_16x16x16bf16_1k(
            onesA, pB[kt], accL1, 0, 0, 0);
      }
      __builtin_amdgcn_s_setprio(0);
    }

    __syncthreads();  // all reads of buf[cur] done; next STAGE may overwrite
  }
  #undef STAGE

  // fused FINAL epilogue: combb(bf16) = comb1 + c0*sparse + c1*slide
  const float c0 =
      (1.f / (1.f + __expf(-kvg[(size_t)qg * KVGW + 257]))) / accL0[0];
  const float c1 =
      (1.f / (1.f + __expf(-kvg[(size_t)qg * KVGW + 258]))) / accL1[0];
  #pragma unroll
  for (int dt = 0; dt < 4; ++dt) {
    const size_t base = ((size_t)qg * NHQ + head) * HD + dt * 16 + quad * 4;
    f32x4 cv = *(const f32x4*)(comb1 + base);
    short4_t o;
    #pragma unroll
    for (int r = 0; r < 4; ++r)
      o[r] = (short)f2bf(cv[r] + c0 * acc0[dt][r] + c1 * acc1[dt][r]);
    *(short4_t*)(combb + base) = o;
  }
}

extern "C" void kernel_launch(void* const* d_in, const int* in_sizes, int n_in,
                              void* d_out, int out_size, void* d_ws, size_t ws_size,
                              hipStream_t stream) {
  const float* x   = (const float*)d_in[0];
  const float* Wq  = (const float*)d_in[1];
  const float* Wk  = (const float*)d_in[2];
  const float* Wv  = (const float*)d_in[3];
  const float* Wo  = (const float*)d_in[4];
  const float* Wg  = (const float*)d_in[5];
  const float* Wck = (const float*)d_in[6];
  const float* Wcv = (const float*)d_in[7];
  float* out = (float*)d_out;
  float* ws = (float*)d_ws;

  float* qbuf   = ws;                           // 4,194,304 f
  float* comb1  = qbuf + 4194304;               // 4,194,304 f
  float* kvg    = comb1 + 4194304;              //   786,432 f
  float* ckb    = kvg + 786432;                 //    16,384 f (bf16 ck+cvT)
  float* cvb    = ckb + 16384;                  //    16,384 f (unused)
  unsigned* sel = (unsigned*)(cvb + 16384);     //     4,096 u32
  ushort* kbf   = (ushort*)(sel + 4096);        //   262,144 u16
  ushort* vtb   = kbf + 262144;                 //   262,144 u16
  ushort* wkvgb = vtb + 262144;                 //   786,432 u16
  ushort* regA  = wkvgb + 786432;               // 4,194,304 u16: xb -> combb
  ushort* regB  = regA + 4194304;               // 4,194,304 u16: wqb -> qbf
  ushort* xb = regA;      ushort* combb = regA;
  ushort* wqb = regB;     ushort* qbf = regB;
  ushort* wob = (ushort*)qbuf;        // fp32 q dead after rope_all

  ushort* ckb16 = (ushort*)ckb;       // 128*2*64 u16 = 32 KB
  ushort* cvtb  = ckb16 + 16384;      // 2*64*128 u16 = 32 KB (within ckb slot)

  const int CV4 = (1048576 + 255) / 256;  // 4M elems / 4 per thread
  cvt_bf<<<CV4, 256, 0, stream>>>(x, xb, 4194304);
  cvt_bf<<<CV4, 256, 0, stream>>>(Wq, wqb, 4194304);
  pack_wkvg<<<(KVGW * 2048 + 255) / 256, 256, 0, stream>>>(Wk, Wv, Wg, wkvgb);

  mgemm<<<dim3(32, 16), 256, 0, stream>>>(xb, wqb, qbuf, 2048, 2048, 2048);
  // kvg GEMM K-split x4 into comb1 scratch (free until comp_attn), then sum.
  mgemm_ks<<<dim3(6, 16, 4), 256, 0, stream>>>(xb, wkvgb, comb1, 2048, KVGW, 2048);
  sum4<<<(786432 / 4 + 255) / 256, 256, 0, stream>>>(comb1, kvg, 786432);

  rope_all<<<2048, 256, 0, stream>>>(qbuf, kvg, qbf, kbf);
  cvt_bf<<<CV4, 256, 0, stream>>>(Wo, wob, 4194304);  // qbuf free after rope
  cvt_vt<<<(262144 + 255) / 256, 256, 0, stream>>>(kvg, vtb);
  compress_kv<<<dim3(128, 2), 256, 0, stream>>>(kvg, Wck, Wcv, ckb16, cvtb);
  comp_attn<<<dim3(128, 2), 512, 0, stream>>>(qbf, ckb16, cvtb, kvg, comb1, sel);
  mfma_attn<<<dim3(32, 2, 8), 512, 0, stream>>>(qbf, kbf, vtb, kvg, sel, comb1, combb);

  mgemm<<<dim3(32, 16), 256, 0, stream>>>(combb, wob, out, 2048, 2048, 2048);
}

// Round 20
// 324.238 us; speedup vs baseline: 1.1265x; 1.0876x over previous
//
#include <hip/hip_runtime.h>
#include <math.h>

#define T_SEQ 2048
#define NHQ 32
#define NG 2
#define HD 64
#define CSTRIDE 16
#define KVGW 384  // fused k|v|gate row width: 128 k + 128 v + 3 gate + pad

// raw v_exp_f32 (computes 2^x). HIP's exp2f() is the PRECISE ocml version
// (~6 extra VALU ops: round-14 VALUBusy 37->50% regression); __expf is
// v_mul(log2e)+v_exp. The builtin is the single-instruction path.
#if defined(__has_builtin)
#if __has_builtin(__builtin_amdgcn_exp2f)
#define EXP2(x) __builtin_amdgcn_exp2f(x)
#endif
#endif
#ifndef EXP2
#define EXP2(x) __expf(0.6931471805599453f * (x))
#endif

typedef __attribute__((ext_vector_type(8))) short short8_t;
typedef __attribute__((ext_vector_type(4))) short short4_t;
typedef __attribute__((ext_vector_type(4))) float f32x4;

__device__ __forceinline__ ushort f2bf(float x) {  // round-to-nearest-even
  union { float f; unsigned u; } c; c.f = x;
  unsigned r = c.u + 0x7fff + ((c.u >> 16) & 1);
  return (ushort)(r >> 16);
}
__device__ __forceinline__ float bf2f(ushort u) {
  union { unsigned u; float f; } c; c.u = ((unsigned)u) << 16;
  return c.f;
}

__device__ __forceinline__ void glds16(const ushort* g, ushort* l) {
  __builtin_amdgcn_global_load_lds(
      (const __attribute__((address_space(1))) unsigned int*)g,
      (__attribute__((address_space(3))) unsigned int*)l, 16, 0, 0);
}

// ---- bf16 MFMA GEMM: C[M,N] = A[M,K] * B[N,K]^T (m97 recipe + XOR swizzle)
// BM=128 x BN=64 tile, 256 thr = 4 waves (wave tile 64x32): at N=2048 grid
// 32x16 = 512 wgs = 2 wg/CU -> independent barriers overlap vmcnt drains.
// MEASURED BEST (round 15/17). 8-wave 32x32 variant regressed +13us (r16).
__global__ __launch_bounds__(256) void mgemm(
    const ushort* __restrict__ A, const ushort* __restrict__ B,
    float* __restrict__ C, int M, int N, int K) {
  __shared__ __align__(16) ushort As[128 * 64];
  __shared__ __align__(16) ushort Bs[64 * 64];
  const int tid = threadIdx.x;
  const int lane = tid & 63, w = tid >> 6;  // 4 waves
  const int quad = lane >> 4, l16 = lane & 15;
  const int m0 = blockIdx.y * 128, n0 = blockIdx.x * 64;
  const int mq = (w & 1) * 64, nq = (w >> 1) * 32;
  f32x4 acc[4][2];
  const f32x4 fz = {0.f, 0.f, 0.f, 0.f};
  #pragma unroll
  for (int i = 0; i < 4; ++i)
    #pragma unroll
    for (int j = 0; j < 2; ++j) acc[i][j] = fz;

  for (int k0 = 0; k0 < K; k0 += 64) {
    __syncthreads();
    #pragma unroll
    for (int j = 0; j < 4; ++j) {  // A: 128 rows x 8 chunks
      int ci = j * 256 + tid;
      int row = ci >> 3, cl = ci & 7;
      int kc = cl ^ (row & 7);
      glds16(A + ((size_t)(m0 + row) * K + k0 + kc * 8), &As[ci * 8]);
    }
    #pragma unroll
    for (int j = 0; j < 2; ++j) {  // B: 64 rows x 8 chunks
      int ci = j * 256 + tid;
      int row = ci >> 3, cl = ci & 7;
      int kc = cl ^ (row & 7);
      glds16(B + ((size_t)(n0 + row) * K + k0 + kc * 8), &Bs[ci * 8]);
    }
    __syncthreads();
    #pragma unroll
    for (int kt = 0; kt < 2; ++kt) {
      short8_t af[4], bf_[2];
      #pragma unroll
      for (int mt = 0; mt < 4; ++mt) {
        int row = mq + mt * 16 + l16;
        int cl = (kt * 4 + quad) ^ (row & 7);
        af[mt] = *(const short8_t*)&As[row * 64 + cl * 8];
      }
      #pragma unroll
      for (int nt = 0; nt < 2; ++nt) {
        int row = nq + nt * 16 + l16;
        int cl = (kt * 4 + quad) ^ (row & 7);
        bf_[nt] = *(const short8_t*)&Bs[row * 64 + cl * 8];
      }
      #pragma unroll
      for (int mt = 0; mt < 4; ++mt)
        #pragma unroll
        for (int nt = 0; nt < 2; ++nt)
          acc[mt][nt] = __builtin_amdgcn_mfma_f32_16x16x32_bf16(
              af[mt], bf_[nt], acc[mt][nt], 0, 0, 0);
    }
  }
  #pragma unroll
  for (int mt = 0; mt < 4; ++mt)
    #pragma unroll
    for (int nt = 0; nt < 2; ++nt)
      #pragma unroll
      for (int r = 0; r < 4; ++r) {
        int m = m0 + mq + mt * 16 + quad * 4 + r;
        int n = n0 + nq + nt * 16 + l16;
        C[(size_t)m * N + n] = acc[mt][nt][r];
      }
}

// ---- K-split mgemm: grid (N/64, M/128, 4); z computes K-quarter partial
// into Cp + z*M*N. For the kvg GEMM (N=384): 96 wgs -> 384 wgs.
__global__ __launch_bounds__(256) void mgemm_ks(
    const ushort* __restrict__ A, const ushort* __restrict__ B,
    float* __restrict__ Cp, int M, int N, int K) {
  __shared__ __align__(16) ushort As[128 * 64];
  __shared__ __align__(16) ushort Bs[64 * 64];
  const int tid = threadIdx.x;
  const int lane = tid & 63, w = tid >> 6;  // 4 waves
  const int quad = lane >> 4, l16 = lane & 15;
  const int m0 = blockIdx.y * 128, n0 = blockIdx.x * 64;
  const int mq = (w & 1) * 64, nq = (w >> 1) * 32;
  const int kq = K >> 2;
  const int kbeg = blockIdx.z * kq, kend = kbeg + kq;
  float* C = Cp + (size_t)blockIdx.z * M * N;
  f32x4 acc[4][2];
  const f32x4 fz = {0.f, 0.f, 0.f, 0.f};
  #pragma unroll
  for (int i = 0; i < 4; ++i)
    #pragma unroll
    for (int j = 0; j < 2; ++j) acc[i][j] = fz;

  for (int k0 = kbeg; k0 < kend; k0 += 64) {
    __syncthreads();
    #pragma unroll
    for (int j = 0; j < 4; ++j) {  // A: 128 rows x 8 chunks
      int ci = j * 256 + tid;
      int row = ci >> 3, cl = ci & 7;
      int kc = cl ^ (row & 7);
      glds16(A + ((size_t)(m0 + row) * K + k0 + kc * 8), &As[ci * 8]);
    }
    #pragma unroll
    for (int j = 0; j < 2; ++j) {  // B: 64 rows x 8 chunks
      int ci = j * 256 + tid;
      int row = ci >> 3, cl = ci & 7;
      int kc = cl ^ (row & 7);
      glds16(B + ((size_t)(n0 + row) * K + k0 + kc * 8), &Bs[ci * 8]);
    }
    __syncthreads();
    #pragma unroll
    for (int kt = 0; kt < 2; ++kt) {
      short8_t af[4], bf_[2];
      #pragma unroll
      for (int mt = 0; mt < 4; ++mt) {
        int row = mq + mt * 16 + l16;
        int cl = (kt * 4 + quad) ^ (row & 7);
        af[mt] = *(const short8_t*)&As[row * 64 + cl * 8];
      }
      #pragma unroll
      for (int nt = 0; nt < 2; ++nt) {
        int row = nq + nt * 16 + l16;
        int cl = (kt * 4 + quad) ^ (row & 7);
        bf_[nt] = *(const short8_t*)&Bs[row * 64 + cl * 8];
      }
      #pragma unroll
      for (int mt = 0; mt < 4; ++mt)
        #pragma unroll
        for (int nt = 0; nt < 2; ++nt)
          acc[mt][nt] = __builtin_amdgcn_mfma_f32_16x16x32_bf16(
              af[mt], bf_[nt], acc[mt][nt], 0, 0, 0);
    }
  }
  #pragma unroll
  for (int mt = 0; mt < 4; ++mt)
    #pragma unroll
    for (int nt = 0; nt < 2; ++nt)
      #pragma unroll
      for (int r = 0; r < 4; ++r) {
        int m = m0 + mq + mt * 16 + quad * 4 + r;
        int n = n0 + nq + nt * 16 + l16;
        C[(size_t)m * N + n] = acc[mt][nt][r];
      }
}

// sum of 4 K-partials (float4-vectorized)
__global__ __launch_bounds__(256) void sum4(const float* __restrict__ p,
                                            float* __restrict__ dst, int n) {
  int i = (blockIdx.x * 256 + threadIdx.x) * 4;
  if (i >= n) return;
  float4 a = *(const float4*)(p + i);
  float4 b = *(const float4*)(p + n + i);
  float4 c = *(const float4*)(p + 2 * (size_t)n + i);
  float4 d = *(const float4*)(p + 3 * (size_t)n + i);
  float4 o = {a.x + b.x + c.x + d.x, a.y + b.y + c.y + d.y,
              a.z + b.z + c.z + d.z, a.w + b.w + c.w + d.w};
  *(float4*)(dst + i) = o;
}

// ---------------- conversions / packing (float4-vectorized, G13) ----------
__global__ __launch_bounds__(256) void cvt_bf(const float* __restrict__ src,
                                              ushort* __restrict__ dst, int n) {
  int i = (blockIdx.x * 256 + threadIdx.x) * 4;
  if (i >= n) return;
  float4 v = *(const float4*)(src + i);
  short4_t o = {(short)f2bf(v.x), (short)f2bf(v.y),
                (short)f2bf(v.z), (short)f2bf(v.w)};
  *(short4_t*)(dst + i) = o;
}

__global__ __launch_bounds__(256) void pack_wkvg(
    const float* __restrict__ Wk, const float* __restrict__ Wv,
    const float* __restrict__ Wg, ushort* __restrict__ dst) {
  int i = blockIdx.x * 256 + threadIdx.x;
  if (i >= KVGW * 2048) return;
  int n = i >> 11, k = i & 2047;
  float v;
  if (n < 128) v = Wk[(size_t)n * 2048 + k];
  else if (n < 256) v = Wv[(size_t)(n - 128) * 2048 + k];
  else if (n < 259) v = Wg[(size_t)(n - 256) * 2048 + k];
  else v = 0.f;
  dst[i] = f2bf(v);
}

// vt[g][d][*] bf16 from kvg v-part (v is NOT roped), with an 8B-slot
// permutation baked into each 64-key block: key k of block blk is stored at
// blk*64 + ((k>>2)^(d&15))*4 + (k&3). mfma_attn stages rows LINEARLY and
// reads slot (kt*4+quad)^l16 -> conflict-free b64 phases (verified r7: 6.39M->0).
__global__ __launch_bounds__(256) void cvt_vt(const float* __restrict__ kvg,
                                              ushort* __restrict__ vt) {
  int i = blockIdx.x * 256 + threadIdx.x;
  if (i >= T_SEQ * NG * HD) return;
  int d = i & 63, g = (i >> 6) & 1, s = i >> 7;
  int blk = s >> 6, k = s & 63;
  int snew = blk * 64 + (((k >> 2) ^ (d & 15)) << 2) + (k & 3);
  vt[((size_t)g * HD + d) * T_SEQ + snew] =
      f2bf(kvg[(size_t)s * KVGW + 128 + g * 64 + d]);
}

// ------- RoPE: q fp32 -> qbf bf16 PRE-SCALED by 0.125*log2(e) so attention
// scores are in the log2 domain: softmax uses raw v_exp_f32 (EXP2) with no
// per-element log2e multiply. Softmax is base-invariant after normalization.
// kvg k-part roped in place + kbf bf16 (NOT scaled).
__global__ __launch_bounds__(256) void rope_all(
    const float* __restrict__ q, float* __restrict__ kvg,
    ushort* __restrict__ qbf, ushort* __restrict__ kbf) {
  const int t = blockIdx.x;
  const float lnb_over = 9.210340371976184f / 32.f;  // ln(10000)/32
  const float QS = 0.18033688011112042f;  // 0.125 * log2(e)
  for (int job = threadIdx.x; job < (NHQ + NG) * 32; job += 256) {
    int h = job >> 5, j = job & 31;
    float inv = expf(-(float)j * lnb_over);
    float fr = (float)t * inv;
    float c_ = cosf(fr), s_ = sinf(fr);
    if (h < NHQ) {
      const float cq = c_ * QS, sq = s_ * QS;
      const float* base = q + ((size_t)t * NHQ + h) * HD;
      float x1 = base[j], x2 = base[j + 32];
      ushort* ob = qbf + ((size_t)t * NHQ + h) * HD;
      ob[j] = f2bf(x1 * cq - x2 * sq);
      ob[j + 32] = f2bf(x2 * cq + x1 * sq);
    } else {
      int g = h - NHQ;
      float* base = kvg + (size_t)t * KVGW + g * 64;
      float x1 = base[j], x2 = base[j + 32];
      float o1 = x1 * c_ - x2 * s_, o2 = x2 * c_ + x1 * s_;
      base[j] = o1; base[j + 32] = o2;
      kbf[(size_t)t * 128 + g * 64 + j] = f2bf(o1);
      kbf[(size_t)t * 128 + g * 64 + j + 32] = f2bf(o2);
    }
  }
}

// ------- compression v3: f-split x4 over grid z (round-18 PMC: the
// monolithic version was 66.6us at 10.9% occupancy / 7.4% VALUBusy —
// 1 wg/CU, 512-iter serial L2-latency chain). grid (127, 2, 4) = 1016 wgs
// (~4 wg/CU, 16 waves/CU), 128 iters/thread; fp32 partials -> compress_c.
__global__ __launch_bounds__(256) void compress_p(
    const float* __restrict__ kvg,
    const float* __restrict__ Wck, const float* __restrict__ Wcv,
    float* __restrict__ pk, float* __restrict__ pv) {
  const int c = blockIdx.x, g = blockIdx.y, z = blockIdx.z;
  const int tid = threadIdx.x;
  const int d = tid & 63, chunk = tid >> 6;
  __shared__ float red[2][4][64];
  float ak = 0.f, av = 0.f;
  const int f0 = z * 512 + chunk * 128;
  #pragma unroll 4
  for (int f = f0; f < f0 + 128; ++f) {
    int i = f >> 6, e = f & 63;
    int trow = c * CSTRIDE + i;  // c<=126 -> trow<=2047, in range
    float kv = kvg[(size_t)trow * KVGW + g * 64 + e];
    float vv = kvg[(size_t)trow * KVGW + 128 + g * 64 + e];
    ak += kv * Wck[((size_t)g * 2048 + f) * HD + d];
    av += vv * Wcv[((size_t)g * 2048 + f) * HD + d];
  }
  red[0][chunk][d] = ak;
  red[1][chunk][d] = av;
  __syncthreads();
  const size_t o = ((size_t)z * 127 + c) * 2 * 64 + (size_t)g * 64;
  if (tid < 64) {
    pk[o + tid] = red[0][0][tid] + red[0][1][tid] + red[0][2][tid] + red[0][3][tid];
  } else if (tid < 128) {
    int dd = tid - 64;
    pv[o + dd] = red[1][0][dd] + red[1][1][dd] + red[1][2][dd] + red[1][3][dd];
  }
}

// combine 4 f-partials -> bf16 ck[c][g][d], cv^T[g][d][c]; c==127 pad = 0.
__global__ __launch_bounds__(256) void compress_c(
    const float* __restrict__ pk, const float* __restrict__ pv,
    ushort* __restrict__ ck16, ushort* __restrict__ cvt16) {
  int i = blockIdx.x * 256 + threadIdx.x;
  if (i >= 128 * NG * HD) return;
  int d = i & 63, g = (i >> 6) & 1, c = i >> 7;
  if (c == 127) {
    ck16[((size_t)127 * NG + g) * HD + d] = 0;
    cvt16[((size_t)g * HD + d) * 128 + 127] = 0;
    return;
  }
  const size_t b = ((size_t)c * 2 + g) * 64 + d;
  const size_t zs = (size_t)127 * 2 * 64;  // 16256
  float sk = pk[b] + pk[b + zs] + pk[b + 2 * zs] + pk[b + 3 * zs];
  float sv = pv[b] + pv[b + zs] + pv[b + 2 * zs] + pv[b + 3 * zs];
  ck16[((size_t)c * NG + g) * HD + d] = f2bf(sk);
  cvt16[((size_t)g * HD + d) * 128 + c] = f2bf(sv);
}

// ------- MFMA compressed attention + block scores + parallel top-16 -------
// grid (128 t-tiles of 16, 2 g), 512 threads = 8 waves x 2 heads each.
// ct-skip: only c-tiles <= ctmax = (t0-16)>>8 are causally reachable
// (uniform per block; mean 4.5/8) -> wave-uniform branch skips ~44%.
__global__ __launch_bounds__(512) void comp_attn(
    const ushort* __restrict__ qbf, const ushort* __restrict__ ck16,
    const ushort* __restrict__ cvt16, const float* __restrict__ kvg,
    float* __restrict__ comb, unsigned* __restrict__ sel) {
  const int tb = 127 - blockIdx.x, g = blockIdx.y;  // LPT tail packing
  const int t0 = tb * 16;
  const int tid = threadIdx.x, lane = tid & 63, w = tid >> 6;
  const int quad = lane >> 4, l16 = lane & 15;
  const int qb = t0 >> 6;  // uniform across the 16 t's of this block
  const int ctmax = (t0 >= 16) ? ((t0 - 16) >> 8) : -1;  // last live c-tile

  __shared__ float colsum[16][129];  // [t_local][c], padded vs bank conflicts
  for (int i = tid; i < 16 * 129; i += 512) ((float*)colsum)[i] = 0.f;
  __syncthreads();

  const int t = t0 + l16;
  const int cmaxv = (t >= 31) ? min(126, (t - 31) >> 4) : -1;
  const int h0 = w * 2;  // two heads per wave

  short8_t qB[2][2];
  #pragma unroll
  for (int hh = 0; hh < 2; ++hh)
    #pragma unroll
    for (int kd = 0; kd < 2; ++kd)
      qB[hh][kd] = *(const short8_t*)(qbf +
          ((size_t)t * NHQ + g * 16 + h0 + hh) * HD + kd * 32 + quad * 8);

  const f32x4 fz = {0.f, 0.f, 0.f, 0.f};
  f32x4 sp[2][8];

  #pragma unroll
  for (int ct = 0; ct < 8; ++ct) {
    if (ct <= ctmax) {
      const ushort* kr = ck16 + ((size_t)(ct * 16 + l16) * NG + g) * HD + quad * 8;
      short8_t kA0 = *(const short8_t*)kr;
      short8_t kA1 = *(const short8_t*)(kr + 32);
      #pragma unroll
      for (int hh = 0; hh < 2; ++hh) {
        f32x4 c0 = __builtin_amdgcn_mfma_f32_16x16x32_bf16(kA0, qB[hh][0], fz, 0, 0, 0);
        sp[hh][ct] = __builtin_amdgcn_mfma_f32_16x16x32_bf16(kA1, qB[hh][1], c0, 0, 0, 0);
      }
    }
  }

  short4_t pB[2][8];
  #pragma unroll
  for (int hh = 0; hh < 2; ++hh) {
    float mx = -INFINITY;
    #pragma unroll
    for (int ct = 0; ct < 8; ++ct) {
      if (ct <= ctmax) {
        #pragma unroll
        for (int r = 0; r < 4; ++r) {
          int c = ct * 16 + quad * 4 + r;
          float s_ = (c <= cmaxv) ? sp[hh][ct][r] : -INFINITY;
          sp[hh][ct][r] = s_;
          mx = fmaxf(mx, s_);
        }
      }
    }
    mx = fmaxf(mx, __shfl_xor(mx, 16));
    mx = fmaxf(mx, __shfl_xor(mx, 32));
    if (mx == -INFINITY) mx = 0.f;  // fully-masked rows (t < 31)
    float ls = 0.f;
    #pragma unroll
    for (int ct = 0; ct < 8; ++ct) {
      if (ct <= ctmax) {
        #pragma unroll
        for (int r = 0; r < 4; ++r) {
          float p = EXP2(sp[hh][ct][r] - mx);
          sp[hh][ct][r] = p;
          ls += p;
        }
      }
    }
    ls += __shfl_xor(ls, 16);
    ls += __shfl_xor(ls, 32);
    float inv = (ls > 0.f) ? 1.f / ls : 0.f;
    #pragma unroll
    for (int ct = 0; ct < 8; ++ct) {
      if (ct <= ctmax) {
        short4_t pk;
        #pragma unroll
        for (int r = 0; r < 4; ++r) {
          float pn = sp[hh][ct][r] * inv;
          sp[hh][ct][r] = pn;
          pk[r] = (short)f2bf(pn);
        }
        pB[hh][ct] = pk;
      }
    }
  }

  #pragma unroll
  for (int ct = 0; ct < 8; ++ct) {
    if (ct <= ctmax) {
      #pragma unroll
      for (int r = 0; r < 4; ++r)
        atomicAdd(&colsum[l16][ct * 16 + quad * 4 + r],
                  sp[0][ct][r] + sp[1][ct][r]);
    }
  }

  f32x4 acc[2][4];
  #pragma unroll
  for (int hh = 0; hh < 2; ++hh)
    #pragma unroll
    for (int dt = 0; dt < 4; ++dt) acc[hh][dt] = fz;
  #pragma unroll
  for (int ct = 0; ct < 8; ++ct) {
    if (ct <= ctmax) {
      short4_t vA[4];
      #pragma unroll
      for (int dt = 0; dt < 4; ++dt)
        vA[dt] = *(const short4_t*)(cvt16 +
            ((size_t)g * HD + dt * 16 + l16) * 128 + ct * 16 + quad * 4);
      #pragma unroll
      for (int hh = 0; hh < 2; ++hh)
        #pragma unroll
        for (int dt = 0; dt < 4; ++dt)
          acc[hh][dt] = __builtin_amdgcn_mfma_f32_16x16x16bf16_1k(
              vA[dt], pB[hh][ct], acc[hh][dt], 0, 0, 0);
    }
  }

  const float g0 = 1.f / (1.f + __expf(-kvg[(size_t)t * KVGW + 256]));
  #pragma unroll
  for (int hh = 0; hh < 2; ++hh)
    #pragma unroll
    for (int dt = 0; dt < 4; ++dt)
      #pragma unroll
      for (int r = 0; r < 4; ++r)
        comb[((size_t)t * NHQ + g * 16 + h0 + hh) * HD + dt * 16 + quad * 4 + r] =
            g0 * acc[hh][dt][r];

  __syncthreads();

  {
    const int tl = tid >> 5;   // 0..15
    const int b = tid & 31;
    float s;
    if (b > qb) s = -INFINITY;
    else if (b == 0 || qb - b < 2) s = INFINITY;
    else {
      s = 0.f;
      #pragma unroll
      for (int i = 0; i < 5; ++i) s += colsum[tl][4 * b - 1 + i];
    }
    unsigned key = (s < 0.f) ? 0u : (__float_as_uint(s) + 1u);
    unsigned msel = 0;
    for (int it = 0; it < 16; ++it) {
      unsigned long long pk =
          (((unsigned long long)key) << 6) | (unsigned)(63 - b);
      #pragma unroll
      for (int off = 16; off >= 1; off >>= 1) {
        unsigned long long o = __shfl_xor(pk, off);
        if (o > pk) pk = o;
      }
      if ((pk >> 6) == 0) break;  // uniform within the 32-group
      int bs = 63 - (int)(pk & 63);
      msel |= 1u << bs;
      if (b == bs) key = 0;
    }
    if (b == 0) sel[(size_t)(t0 + tl) * NG + g] = msel;
  }
}

// ------- MFMA flash attention v11: mode-fused + fused FINAL epilogue +
// raw v_exp_f32 softmax (EXP2 builtin) + wave-level mode-0 skip.
// grid (32 qb, 2 g, 8 hgp). (512,2): 128-VGPR cap (60 used), no spill.
__global__ __launch_bounds__(512, 2) void mfma_attn(
    const ushort* __restrict__ qb16, const ushort* __restrict__ kb16,
    const ushort* __restrict__ vtb, const float* __restrict__ kvg,
    const unsigned* __restrict__ sel, const float* __restrict__ comb1,
    ushort* __restrict__ combb) {
  const int g = blockIdx.y;
  const int hgp = blockIdx.z;
  const int qb = (hgp >= 4) ? blockIdx.x : 31 - blockIdx.x;  // pair-balance
  const int tid = threadIdx.x, lane = tid & 63, w = tid >> 6;  // 8 waves
  const int quad = lane >> 4, l16 = lane & 15;
  const int head = g * 16 + hgp * 2 + (w >> 2);
  const int t0 = qb * 64;

  __shared__ __align__(16) ushort Ks[2][64 * 64];  // 16 KB (dbuf)
  __shared__ __align__(16) ushort Vs[2][64 * 64];  // 16 KB (dbuf)
  __shared__ unsigned sel_s[64];

  if (tid < 64) sel_s[tid] = sel[(size_t)(t0 + tid) * NG + g];
  __syncthreads();

  // my 16 queries (one 16-row tile per wave)
  const int qg = t0 + (w & 3) * 16 + l16;
  const unsigned sbq = sel_s[(w & 3) * 16 + l16];

  short8_t qB0 = *(const short8_t*)(qb16 +
      ((size_t)qg * NHQ + head) * HD + quad * 8);
  short8_t qB1 = *(const short8_t*)(qb16 +
      ((size_t)qg * NHQ + head) * HD + 32 + quad * 8);

  float m0 = -1e30f, m1 = -1e30f;
  f32x4 acc0[4], acc1[4], accL0, accL1;
  const f32x4 fz = {0.f, 0.f, 0.f, 0.f};
  #pragma unroll
  for (int dt = 0; dt < 4; ++dt) { acc0[dt] = fz; acc1[dt] = fz; }
  accL0 = fz; accL1 = fz;
  const short4_t onesA = {(short)0x3F80, (short)0x3F80,
                          (short)0x3F80, (short)0x3F80};  // bf16 1.0 x4

  // block lists: sparse union (all 8 waves identical) and sliding window
  unsigned uni = sel_s[lane];
  #pragma unroll
  for (int off = 32; off >= 1; off >>= 1) uni |= __shfl_xor(uni, off);
  const int b0w = (qb > 8) ? qb - 8 : 0;
  const unsigned wmask = ((1u << (qb - b0w + 1)) - 1u) << b0w;
  unsigned lrem = uni | wmask;
  const int nb = __popc(lrem);

  // stage K (XOR 16B chunk swizzle) and V^T (linear; perm pre-baked in vtb)
  #define STAGE(buf, blk)                                                     \
    {                                                                         \
      const int blk_ = (blk);                                                 \
      const int row = tid >> 3, cl = tid & 7;                                 \
      const int kck = cl ^ (row & 7);                                         \
      glds16(kb16 + (size_t)(blk_ * 64 + row) * 128 + g * 64 + kck * 8,       \
             &Ks[buf][tid * 8]);                                              \
      glds16(vtb + ((size_t)g * 64 + row) * 2048 + blk_ * 64 + cl * 8,        \
             &Vs[buf][tid * 8]);                                              \
    }

  int blkcur = __ffs(lrem) - 1; lrem &= lrem - 1;
  STAGE(0, blkcur);
  __syncthreads();  // tile 0 resident

  const int e = l16 & 7;  // K-read perm

  for (int ib = 0; ib < nb; ++ib) {
    const int cur = ib & 1;
    const int blk = blkcur;
    if (ib + 1 < nb) {  // prefetch next tile into other buffer
      blkcur = __ffs(lrem) - 1; lrem &= lrem - 1;
      STAGE(cur ^ 1, blkcur);
    }

    // S^T = K Q^T from LDS — computed ONCE, shared by both modes
    f32x4 sp[4];
    __builtin_amdgcn_s_setprio(1);
    #pragma unroll
    for (int kt = 0; kt < 4; ++kt) {
      const ushort* kr = &Ks[cur][(kt * 16 + l16) * 64];
      short8_t kA0 = *(const short8_t*)(kr + ((quad ^ e) * 8));
      short8_t kA1 = *(const short8_t*)(kr + ((quad ^ e ^ 4) * 8));
      f32x4 c = __builtin_amdgcn_mfma_f32_16x16x32_bf16(kA0, qB0, fz, 0, 0, 0);
      sp[kt] = __builtin_amdgcn_mfma_f32_16x16x32_bf16(kA1, qB1, c, 0, 0, 0);
    }
    __builtin_amdgcn_s_setprio(0);

    const bool diag = (blk == qb);
    const bool wedge = (blk == qb - 8);           // window-edge (qb>=8 only)
    const bool inU = ((uni >> blk) & 1u) != 0;    // uniform
    const bool inW = ((wmask >> blk) & 1u) != 0;  // uniform
    const bool selq = ((sbq >> blk) & 1u) != 0;   // per-query

    // shared raw row-max (valid for all fully-unmasked cases)
    float rm = -INFINITY;
    #pragma unroll
    for (int kt = 0; kt < 4; ++kt)
      #pragma unroll
      for (int r = 0; r < 4; ++r) rm = fmaxf(rm, sp[kt][r]);
    rm = fmaxf(rm, __shfl_xor(rm, 16));
    rm = fmaxf(rm, __shfl_xor(rm, 32));

    // ---- mode 0: sparse (sel); skip if NO query in this wave selected it
    if (inU && __any(selq)) {
      float mx;
      if (!diag) {
        mx = selq ? rm : -INFINITY;
      } else {
        mx = -INFINITY;
        #pragma unroll
        for (int kt = 0; kt < 4; ++kt)
          #pragma unroll
          for (int r = 0; r < 4; ++r) {
            int key = blk * 64 + kt * 16 + quad * 4 + r;
            bool ok = selq && (key <= qg);
            mx = ok ? fmaxf(mx, sp[kt][r]) : mx;
          }
        mx = fmaxf(mx, __shfl_xor(mx, 16));
        mx = fmaxf(mx, __shfl_xor(mx, 32));
      }
      if (!__all(mx <= m0 + 11.f)) {  // T13 defer-max (log2 domain)
        float mnew = fmaxf(m0, mx);
        float alpha = EXP2(m0 - mnew);
        #pragma unroll
        for (int dt = 0; dt < 4; ++dt)
          #pragma unroll
          for (int r = 0; r < 4; ++r) acc0[dt][r] *= alpha;
        #pragma unroll
        for (int r = 0; r < 4; ++r) accL0[r] *= alpha;
        m0 = mnew;
      }
      short4_t pB[4];
      #pragma unroll
      for (int kt = 0; kt < 4; ++kt) {
        union { unsigned u[2]; short4_t s; } pk;
        if (!diag) {
          float p0 = EXP2(sp[kt][0] - m0), p1 = EXP2(sp[kt][1] - m0);
          float p2 = EXP2(sp[kt][2] - m0), p3 = EXP2(sp[kt][3] - m0);
          asm("v_cvt_pk_bf16_f32 %0, %1, %2" : "=v"(pk.u[0]) : "v"(p0), "v"(p1));
          asm("v_cvt_pk_bf16_f32 %0, %1, %2" : "=v"(pk.u[1]) : "v"(p2), "v"(p3));
          pk.u[0] = selq ? pk.u[0] : 0u;
          pk.u[1] = selq ? pk.u[1] : 0u;
        } else {
          float p[4];
          #pragma unroll
          for (int r = 0; r < 4; ++r) {
            int key = blk * 64 + kt * 16 + quad * 4 + r;
            bool ok = selq && (key <= qg);
            p[r] = ok ? EXP2(sp[kt][r] - m0) : 0.f;
          }
          asm("v_cvt_pk_bf16_f32 %0, %1, %2" : "=v"(pk.u[0]) : "v"(p[0]), "v"(p[1]));
          asm("v_cvt_pk_bf16_f32 %0, %1, %2" : "=v"(pk.u[1]) : "v"(p[2]), "v"(p[3]));
        }
        pB[kt] = pk.s;
      }
      __builtin_amdgcn_s_setprio(1);
      #pragma unroll
      for (int kt = 0; kt < 4; ++kt) {
        #pragma unroll
        for (int dt = 0; dt < 4; ++dt) {
          short4_t vA = *(const short4_t*)(&Vs[cur][(dt * 16 + l16) * 64 +
                                                    (((kt * 4 + quad) ^ l16) << 2)]);
          acc0[dt] = __builtin_amdgcn_mfma_f32_16x16x16bf16_1k(
              vA, pB[kt], acc0[dt], 0, 0, 0);
        }
        accL0 = __builtin_amdgcn_mfma_f32_16x16x16bf16_1k(
            onesA, pB[kt], accL0, 0, 0, 0);
      }
      __builtin_amdgcn_s_setprio(0);
    }

    // ---- mode 1: sliding window ----
    if (inW) {
      float mx;
      if (!diag && !wedge) {
        mx = rm;  // fully valid block
      } else {
        mx = -INFINITY;
        #pragma unroll
        for (int kt = 0; kt < 4; ++kt)
          #pragma unroll
          for (int r = 0; r < 4; ++r) {
            int key = blk * 64 + kt * 16 + quad * 4 + r;
            bool ok = (key <= qg) && (qg - key <= 512);
            mx = ok ? fmaxf(mx, sp[kt][r]) : mx;
          }
        mx = fmaxf(mx, __shfl_xor(mx, 16));
        mx = fmaxf(mx, __shfl_xor(mx, 32));
      }
      if (!__all(mx <= m1 + 11.f)) {  // T13 defer-max (log2 domain)
        float mnew = fmaxf(m1, mx);
        float alpha = EXP2(m1 - mnew);
        #pragma unroll
        for (int dt = 0; dt < 4; ++dt)
          #pragma unroll
          for (int r = 0; r < 4; ++r) acc1[dt][r] *= alpha;
        #pragma unroll
        for (int r = 0; r < 4; ++r) accL1[r] *= alpha;
        m1 = mnew;
      }
      short4_t pB[4];
      #pragma unroll
      for (int kt = 0; kt < 4; ++kt) {
        union { unsigned u[2]; short4_t s; } pk;
        if (!diag && !wedge) {
          float p0 = EXP2(sp[kt][0] - m1), p1 = EXP2(sp[kt][1] - m1);
          float p2 = EXP2(sp[kt][2] - m1), p3 = EXP2(sp[kt][3] - m1);
          asm("v_cvt_pk_bf16_f32 %0, %1, %2" : "=v"(pk.u[0]) : "v"(p0), "v"(p1));
          asm("v_cvt_pk_bf16_f32 %0, %1, %2" : "=v"(pk.u[1]) : "v"(p2), "v"(p3));
        } else {
          float p[4];
          #pragma unroll
          for (int r = 0; r < 4; ++r) {
            int key = blk * 64 + kt * 16 + quad * 4 + r;
            bool ok = (key <= qg) && (qg - key <= 512);
            p[r] = ok ? EXP2(sp[kt][r] - m1) : 0.f;
          }
          asm("v_cvt_pk_bf16_f32 %0, %1, %2" : "=v"(pk.u[0]) : "v"(p[0]), "v"(p[1]));
          asm("v_cvt_pk_bf16_f32 %0, %1, %2" : "=v"(pk.u[1]) : "v"(p[2]), "v"(p[3]));
        }
        pB[kt] = pk.s;
      }
      __builtin_amdgcn_s_setprio(1);
      #pragma unroll
      for (int kt = 0; kt < 4; ++kt) {
        #pragma unroll
        for (int dt = 0; dt < 4; ++dt) {
          short4_t vA = *(const short4_t*)(&Vs[cur][(dt * 16 + l16) * 64 +
                                                    (((kt * 4 + quad) ^ l16) << 2)]);
          acc1[dt] = __builtin_amdgcn_mfma_f32_16x16x16bf16_1k(
              vA, pB[kt], acc1[dt], 0, 0, 0);
        }
        accL1 = __builtin_amdgcn_mfma_f32_16x16x16bf16_1k(
            onesA, pB[kt], accL1, 0, 0, 0);
      }
      __builtin_amdgcn_s_setprio(0);
    }

    __syncthreads();  // all reads of buf[cur] done; next STAGE may overwrite
  }
  #undef STAGE

  // fused FINAL epilogue: combb(bf16) = comb1 + c0*sparse + c1*slide
  const float c0 =
      (1.f / (1.f + __expf(-kvg[(size_t)qg * KVGW + 257]))) / accL0[0];
  const float c1 =
      (1.f / (1.f + __expf(-kvg[(size_t)qg * KVGW + 258]))) / accL1[0];
  #pragma unroll
  for (int dt = 0; dt < 4; ++dt) {
    const size_t base = ((size_t)qg * NHQ + head) * HD + dt * 16 + quad * 4;
    f32x4 cv = *(const f32x4*)(comb1 + base);
    short4_t o;
    #pragma unroll
    for (int r = 0; r < 4; ++r)
      o[r] = (short)f2bf(cv[r] + c0 * acc0[dt][r] + c1 * acc1[dt][r]);
    *(short4_t*)(combb + base) = o;
  }
}

extern "C" void kernel_launch(void* const* d_in, const int* in_sizes, int n_in,
                              void* d_out, int out_size, void* d_ws, size_t ws_size,
                              hipStream_t stream) {
  const float* x   = (const float*)d_in[0];
  const float* Wq  = (const float*)d_in[1];
  const float* Wk  = (const float*)d_in[2];
  const float* Wv  = (const float*)d_in[3];
  const float* Wo  = (const float*)d_in[4];
  const float* Wg  = (const float*)d_in[5];
  const float* Wck = (const float*)d_in[6];
  const float* Wcv = (const float*)d_in[7];
  float* out = (float*)d_out;
  float* ws = (float*)d_ws;

  float* qbuf   = ws;                           // 4,194,304 f
  float* comb1  = qbuf + 4194304;               // 4,194,304 f
  float* kvg    = comb1 + 4194304;              //   786,432 f
  float* ckb    = kvg + 786432;                 //    16,384 f (bf16 ck+cvT)
  float* cvb    = ckb + 16384;                  //    16,384 f (unused)
  unsigned* sel = (unsigned*)(cvb + 16384);     //     4,096 u32
  ushort* kbf   = (ushort*)(sel + 4096);        //   262,144 u16
  ushort* vtb   = kbf + 262144;                 //   262,144 u16
  ushort* wkvgb = vtb + 262144;                 //   786,432 u16
  ushort* regA  = wkvgb + 786432;               // 4,194,304 u16: xb -> combb
  ushort* regB  = regA + 4194304;               // 4,194,304 u16: wqb -> qbf
  ushort* xb = regA;      ushort* combb = regA;
  ushort* wqb = regB;     ushort* qbf = regB;
  ushort* wob = (ushort*)qbuf;        // fp32 q dead after rope_all

  ushort* ckb16 = (ushort*)ckb;       // 128*2*64 u16 = 32 KB
  ushort* cvtb  = ckb16 + 16384;      // 2*64*128 u16 = 32 KB (within ckb slot)
  float* cprt_k = comb1;              // compress f-partials (free window)
  float* cprt_v = comb1 + 65024;      // 4*127*2*64 = 65024 floats each

  const int CV4 = (1048576 + 255) / 256;  // 4M elems / 4 per thread
  cvt_bf<<<CV4, 256, 0, stream>>>(x, xb, 4194304);
  cvt_bf<<<CV4, 256, 0, stream>>>(Wq, wqb, 4194304);
  pack_wkvg<<<(KVGW * 2048 + 255) / 256, 256, 0, stream>>>(Wk, Wv, Wg, wkvgb);

  mgemm<<<dim3(32, 16), 256, 0, stream>>>(xb, wqb, qbuf, 2048, 2048, 2048);
  // kvg GEMM K-split x4 into comb1 scratch (free until comp_attn), then sum.
  mgemm_ks<<<dim3(6, 16, 4), 256, 0, stream>>>(xb, wkvgb, comb1, 2048, KVGW, 2048);
  sum4<<<(786432 / 4 + 255) / 256, 256, 0, stream>>>(comb1, kvg, 786432);

  rope_all<<<2048, 256, 0, stream>>>(qbuf, kvg, qbf, kbf);
  cvt_bf<<<CV4, 256, 0, stream>>>(Wo, wob, 4194304);  // qbuf free after rope
  cvt_vt<<<(262144 + 255) / 256, 256, 0, stream>>>(kvg, vtb);
  compress_p<<<dim3(127, 2, 4), 256, 0, stream>>>(kvg, Wck, Wcv, cprt_k, cprt_v);
  compress_c<<<(16384 + 255) / 256, 256, 0, stream>>>(cprt_k, cprt_v, ckb16, cvtb);
  comp_attn<<<dim3(128, 2), 512, 0, stream>>>(qbf, ckb16, cvtb, kvg, comb1, sel);
  mfma_attn<<<dim3(32, 2, 8), 512, 0, stream>>>(qbf, kbf, vtb, kvg, sel, comb1, combb);

  mgemm<<<dim3(32, 16), 256, 0, stream>>>(combb, wob, out, 2048, 2048, 2048);
}